// Round 3
// baseline (659.135 us; speedup 1.0000x reference)
//
#include <hip/hip_runtime.h>
#include <hip/hip_bf16.h>

// PropNet fused MFMA-bf16 implementation for MI355X (gfx950).
// B=2 N=64 R=16 D=64 H=256 EOUT=64 PSTEP=2
// node rows nr = (b*64+i)*16 + r            (2048)
// edge rows er = ((b*64+i)*64 + j)*16 + r   (131072)
//
// R2 changes vs R1 (occupancy attack: was 1 block/CU, MfmaUtil 16%):
//  - kstep2pred uses ONE 32KB LDS tile, time-multiplexed (eff->h->eff2->e0->p);
//    e0 is recomputed in place mid-chain instead of held in a 2nd buffer.
//  - __launch_bounds__(256,4) on both kstep kernels (VGPR cap 128) ->
//    target 4 blocks/CU (LDS 4x32KB=128 <= 160KB).
//  - eff is stored as a per-tile 32KB "LDS image" (swizzle baked in); kstep1
//    writes it, kstep2pred stages it via async global_load_lds (16B/lane).
//
// All GEMMs: v_mfma_f32_16x16x32_bf16. Weights pre-packed into fragment order
// with the SAME (lane,elem)->k map as the LDS A-fragment reads, so any k-map
// mismatch vs HW cancels. LDS tiles XOR-swizzled: byte ^= (row&7)<<4.

typedef __attribute__((ext_vector_type(8))) short short8;
typedef __attribute__((ext_vector_type(4))) float f32x4;
typedef __attribute__((ext_vector_type(2))) unsigned int u32x2;

#define DI __device__ __forceinline__

// ---------------- workspace layout (bytes) ----------------
constexpr size_t WF_SZ = 131072;            // 256x256 bf16 frag matrix
// full 256x256 frag matrices, index:
// 0 ep0W1c(=ep0W1[512:768]) 1 ep0W2 2 ep1W1c 3 ep1W2 4 prW1a(=prW1[0:256])
// 5 prW1b(=prW1[256:512]) 6 E1w(=ep0W1[0:256]) 7 E2w(=ep0W1[256:512])
// 8 NE2w(=npW1[256:512]) 9 NAGGw(=npW1[512:768]) 10 NE1w(=npW1[0:256])
// 11 npW2 12 ep1Aw(=ep1W1[0:256]) 13 ep1Bw(=ep1W1[256:512])
constexpr size_t OFF_NEW  = 14 * WF_SZ;     // neW   64x256 frag (32 KB)
constexpr size_t OFF_EE1  = OFF_NEW + 32768; // eeW[0:64]
constexpr size_t OFF_EE2  = OFF_EE1 + 32768; // eeW[64:128]
constexpr size_t OFF_PW2  = OFF_EE2 + 32768; // prW2 256x64 frag
constexpr size_t OFF_NENC = OFF_PW2 + 32768; // node_enc bf16 [2048,256] 1MB
constexpr size_t OFF_X1   = OFF_NENC + (size_t)2048 * 256 * 2;
constexpr size_t SM = (size_t)2048 * 256 * 4;
constexpr size_t OFF_X2  = OFF_X1 + SM;
constexpr size_t OFF_E1  = OFF_X2 + SM;
constexpr size_t OFF_E2  = OFF_E1 + SM;
constexpr size_t OFF_NE1 = OFF_E2 + SM;
constexpr size_t OFF_AGG = OFF_NE1 + SM;
constexpr size_t OFF_IMG = OFF_AGG + SM;     // eff LDS-images: 2048 x 32KB = 64 MiB
// total ~79 MB

DI unsigned short f2bf(float f) {
    unsigned u = __builtin_bit_cast(unsigned, f);
    u += 0x7fffu + ((u >> 16) & 1u);
    return (unsigned short)(u >> 16);
}

// (lane-group g, element e) -> k offset within a 32-wide K tile.
DI int kmap(int g, int e) { return 4 * g + (e & 3) + ((e >> 2) << 4); }

// async 16B/lane global->LDS copy (wave-uniform LDS base, per-lane global src)
DI void dma16(const void* g, void* l) {
    __builtin_amdgcn_global_load_lds((const __attribute__((address_space(1))) void*)g,
                                     (__attribute__((address_space(3))) void*)l, 16, 0, 0);
}

// ---------------- weight repack: f32 [K x ld] -> bf16 fragment order ----------------
__global__ __launch_bounds__(64) void kconv(const float* ep0W1, const float* ep0W2,
                                            const float* ep1W1, const float* ep1W2,
                                            const float* prW1, const float* prW2,
                                            const float* npW1, const float* npW2,
                                            const float* neW, const float* eeW,
                                            unsigned short* wsu)
{
    int bid = blockIdx.x, l = threadIdx.x;
    const float* src; unsigned short* dst; int NT = 16, ld = 256, f;
    if (bid < 1792) {
        int m = bid >> 7; f = bid & 127;
        switch (m) {
            case 0:  src = ep0W1 + 512 * 256; break;
            case 1:  src = ep0W2;             break;
            case 2:  src = ep1W1 + 512 * 256; break;
            case 3:  src = ep1W2;             break;
            case 4:  src = prW1;              break;
            case 5:  src = prW1 + 256 * 256;  break;
            case 6:  src = ep0W1;             break;
            case 7:  src = ep0W1 + 256 * 256; break;
            case 8:  src = npW1 + 256 * 256;  break;
            case 9:  src = npW1 + 512 * 256;  break;
            case 10: src = npW1;              break;
            case 11: src = npW2;              break;
            case 12: src = ep1W1;             break;
            default: src = ep1W1 + 256 * 256; break;
        }
        dst = wsu + (size_t)m * (WF_SZ / 2);
    } else if (bid < 1888) {
        int m = (bid - 1792) >> 5; f = (bid - 1792) & 31;
        src = (m == 0) ? neW : (m == 1) ? eeW : eeW + 64 * 256;
        dst = wsu + ((m == 0) ? OFF_NEW : (m == 1) ? OFF_EE1 : OFF_EE2) / 2;
    } else {
        f = bid - 1888; NT = 4; ld = 64; src = prW2; dst = wsu + OFF_PW2 / 2;
    }
    int kt = f / NT, nt = f % NT;
    int g = l >> 4, c = nt * 16 + (l & 15);
    unsigned short* o = dst + (size_t)((kt * NT + nt) * 64 + l) * 8;
#pragma unroll
    for (int e = 0; e < 8; ++e) {
        int k = 32 * kt + kmap(g, e);
        o[e] = f2bf(src[(size_t)k * ld + c]);
    }
}

// ---------------- MFMA tile helpers ----------------
// LDS tile: rows x (LDB bytes), XOR swizzle byte ^= (row&7)<<4
template <int LDB>
DI short8 load_afrag(const unsigned char* lds, int row, int kt, int g) {
    int sw = (row & 7) << 4;
    int kb = 64 * kt + 8 * g;
    union { short8 s; u32x2 u[2]; } u_;
    u_.u[0] = *(const u32x2*)(lds + row * LDB + (kb ^ sw));
    u_.u[1] = *(const u32x2*)(lds + row * LDB + ((kb + 32) ^ sw));
    return u_.s;
}

DI void zero_acc(f32x4 (&acc)[4][4]) {
#pragma unroll
    for (int mi = 0; mi < 4; ++mi)
#pragma unroll
        for (int ni = 0; ni < 4; ++ni) acc[mi][ni] = (f32x4){0.f, 0.f, 0.f, 0.f};
}

// acc += Atile(64 x 32*KT, LDS) @ W(32*KT x 256, frag order); wave wv owns cols 64*wv..+63
template <int KT, int LDB>
DI void gemm_tile(const unsigned char* lds, const unsigned short* Wf,
                  f32x4 (&acc)[4][4], int wv, int l) {
    const int g = l >> 4, l15 = l & 15;
    for (int kt = 0; kt < KT; ++kt) {
        short8 af[4];
#pragma unroll
        for (int mi = 0; mi < 4; ++mi) af[mi] = load_afrag<LDB>(lds, 16 * mi + l15, kt, g);
        short8 bf[4];
#pragma unroll
        for (int ni = 0; ni < 4; ++ni)
            bf[ni] = *(const short8*)(Wf + (size_t)((kt * 16 + 4 * wv + ni) * 64 + l) * 8);
#pragma unroll
        for (int ni = 0; ni < 4; ++ni)
#pragma unroll
            for (int mi = 0; mi < 4; ++mi)
                acc[mi][ni] = __builtin_amdgcn_mfma_f32_16x16x32_bf16(af[mi], bf[ni], acc[mi][ni], 0, 0, 0);
    }
}

DI void store_tile_f32(float* dst, int r0, f32x4 (&acc)[4][4], int wv, int l) {
    int g = l >> 4, l15 = l & 15;
#pragma unroll
    for (int ni = 0; ni < 4; ++ni) {
        int col = 64 * wv + 16 * ni + l15;
#pragma unroll
        for (int mi = 0; mi < 4; ++mi)
#pragma unroll
            for (int q = 0; q < 4; ++q)
                dst[(size_t)(r0 + 16 * mi + 4 * g + q) * 256 + col] = acc[mi][ni][q];
    }
}

// ---------------- node path: encoder + edge-enc partials + E1/E2/NE1 ----------------
__global__ __launch_bounds__(256) void knode12(const float* node_rep, const float* neb,
        const unsigned short* neWf, const unsigned short* eeW1f, const unsigned short* eeW2f,
        const unsigned short* E1wf, const unsigned short* E2wf, const unsigned short* NE1wf,
        unsigned short* node_enc, float* X1, float* X2, float* E1, float* E2, float* NE1)
{
    __shared__ __align__(16) unsigned char ldsA[64 * 128];
    __shared__ __align__(16) unsigned char ldsB[64 * 512];
    const int r0 = blockIdx.x * 64, tid = threadIdx.x;
    {
        int row = tid >> 2, c0 = (tid & 3) * 16;
        const float* src = node_rep + (size_t)(r0 + row) * 64 + c0;
        union { short8 s; unsigned short u[8]; } v0, v1;
#pragma unroll
        for (int e = 0; e < 8; ++e) { v0.u[e] = f2bf(src[e]); v1.u[e] = f2bf(src[8 + e]); }
        int sw = (row & 7) << 4;
        *(short8*)&ldsA[row * 128 + ((c0 * 2) ^ sw)] = v0.s;
        *(short8*)&ldsA[row * 128 + ((c0 * 2 + 16) ^ sw)] = v1.s;
    }
    __syncthreads();
    const int l = tid & 63, wv = tid >> 6, g = l >> 4, l15 = l & 15;
    f32x4 acc[4][4];
    // node_enc = relu(node_rep @ neW + neb) -> bf16 ldsB + global
    zero_acc(acc);
    gemm_tile<2, 128>(ldsA, neWf, acc, wv, l);
#pragma unroll
    for (int ni = 0; ni < 4; ++ni) {
        int col = 64 * wv + 16 * ni + l15;
        float bb = neb[col];
#pragma unroll
        for (int mi = 0; mi < 4; ++mi)
#pragma unroll
            for (int q = 0; q < 4; ++q) {
                int row = 16 * mi + 4 * g + q;
                unsigned short bv = f2bf(fmaxf(acc[mi][ni][q] + bb, 0.f));
                *(unsigned short*)&ldsB[row * 512 + ((col * 2) ^ ((row & 7) << 4))] = bv;
                node_enc[(size_t)(r0 + row) * 256 + col] = bv;
            }
    }
    // X1 = node_rep @ eeW[:64], X2 = node_rep @ eeW[64:]
    zero_acc(acc);
    gemm_tile<2, 128>(ldsA, eeW1f, acc, wv, l);
    store_tile_f32(X1, r0, acc, wv, l);
    zero_acc(acc);
    gemm_tile<2, 128>(ldsA, eeW2f, acc, wv, l);
    store_tile_f32(X2, r0, acc, wv, l);
    __syncthreads();   // all ldsB writes done before K=256 gemms read it
    zero_acc(acc);
    gemm_tile<8, 512>(ldsB, E1wf, acc, wv, l);
    store_tile_f32(E1, r0, acc, wv, l);
    zero_acc(acc);
    gemm_tile<8, 512>(ldsB, E2wf, acc, wv, l);
    store_tile_f32(E2, r0, acc, wv, l);
    zero_acc(acc);
    gemm_tile<8, 512>(ldsB, NE1wf, acc, wv, l);
    store_tile_f32(NE1, r0, acc, wv, l);
}

// ---------------- node update chain (step-1) + E1_1/E2_1 ----------------
__global__ __launch_bounds__(256) void knode3(const unsigned short* node_enc, const float* agg,
        const float* NE1, const float* npb1, const float* npb2,
        const unsigned short* NE2wf, const unsigned short* NAGGwf, const unsigned short* npW2f,
        const unsigned short* ep1Awf, const unsigned short* ep1Bwf,
        float* E1, float* E2)
{
    __shared__ __align__(16) unsigned char ldsA[64 * 512];
    __shared__ __align__(16) unsigned char ldsB[64 * 512];
    const int r0 = blockIdx.x * 64, tid = threadIdx.x;
    {
        int row = tid >> 2, cbase = (tid & 3) * 64;
        int sw = (row & 7) << 4;
#pragma unroll
        for (int cc = 0; cc < 4; ++cc) {
            int c0 = cbase + cc * 16;
            short8 lo = *(const short8*)(node_enc + (size_t)(r0 + row) * 256 + c0);
            short8 hi = *(const short8*)(node_enc + (size_t)(r0 + row) * 256 + c0 + 8);
            *(short8*)&ldsA[row * 512 + ((c0 * 2) ^ sw)] = lo;
            *(short8*)&ldsA[row * 512 + ((c0 * 2 + 16) ^ sw)] = hi;
            union { short8 s; unsigned short u[8]; } v0, v1;
            const float* asrc = agg + (size_t)(r0 + row) * 256 + c0;
#pragma unroll
            for (int e = 0; e < 8; ++e) { v0.u[e] = f2bf(asrc[e]); v1.u[e] = f2bf(asrc[8 + e]); }
            *(short8*)&ldsB[row * 512 + ((c0 * 2) ^ sw)] = v0.s;
            *(short8*)&ldsB[row * 512 + ((c0 * 2 + 16) ^ sw)] = v1.s;
        }
    }
    __syncthreads();
    const int l = tid & 63, wv = tid >> 6, g = l >> 4, l15 = l & 15;
    f32x4 acc[4][4];
    // g = relu(NE1 + node_enc@NE2w + agg@NAGGw + npb1) -> bf16 ldsA
    zero_acc(acc);
    gemm_tile<8, 512>(ldsA, NE2wf, acc, wv, l);
    gemm_tile<8, 512>(ldsB, NAGGwf, acc, wv, l);
    __syncthreads();
#pragma unroll
    for (int ni = 0; ni < 4; ++ni) {
        int col = 64 * wv + 16 * ni + l15;
        float bb = npb1[col];
#pragma unroll
        for (int mi = 0; mi < 4; ++mi)
#pragma unroll
            for (int q = 0; q < 4; ++q) {
                int row = 16 * mi + 4 * g + q;
                float v = fmaxf(acc[mi][ni][q] + NE1[(size_t)(r0 + row) * 256 + col] + bb, 0.f);
                *(unsigned short*)&ldsA[row * 512 + ((col * 2) ^ ((row & 7) << 4))] = f2bf(v);
            }
    }
    __syncthreads();
    // nf = relu(g @ npW2 + npb2) -> bf16 ldsB
    zero_acc(acc);
    gemm_tile<8, 512>(ldsA, npW2f, acc, wv, l);
    __syncthreads();
#pragma unroll
    for (int ni = 0; ni < 4; ++ni) {
        int col = 64 * wv + 16 * ni + l15;
        float bb = npb2[col];
#pragma unroll
        for (int mi = 0; mi < 4; ++mi)
#pragma unroll
            for (int q = 0; q < 4; ++q) {
                int row = 16 * mi + 4 * g + q;
                *(unsigned short*)&ldsB[row * 512 + ((col * 2) ^ ((row & 7) << 4))] =
                    f2bf(fmaxf(acc[mi][ni][q] + bb, 0.f));
            }
    }
    __syncthreads();
    // E1 = nf @ ep1W1[0:256], E2 = nf @ ep1W1[256:512]
    zero_acc(acc);
    gemm_tile<8, 512>(ldsB, ep1Awf, acc, wv, l);
    store_tile_f32(E1, r0, acc, wv, l);
    zero_acc(acc);
    gemm_tile<8, 512>(ldsB, ep1Bwf, acc, wv, l);
    store_tile_f32(E2, r0, acc, wv, l);
}

// ---------------- fused edge propagation step 0 (writes eff-image + agg) ----------------
__global__ __launch_bounds__(256, 4) void kstep1(const float* X1, const float* X2, const float* eeb,
                                                 const float* E1, const float* E2,
                                                 const float* b1, const float* b2,
                                                 const unsigned short* WfA, const unsigned short* WfB,
                                                 unsigned char* img, float* agg)
{
    __shared__ __align__(16) unsigned char T[64 * 512];
    const int bir = blockIdx.x, tid = threadIdx.x;
    const int b = bir >> 10, r = bir & 15;

    {   // phase 0: build e0 tile (rows = senders j)
        int rlo = tid >> 5;
        int c0 = (tid & 31) * 8;
        for (int p = 0; p < 8; ++p) {
            int row = p * 8 + rlo;
            union { short8 s; unsigned short u[8]; } v;
            int nrj = b * 1024 + row * 16 + r;
#pragma unroll
            for (int e = 0; e < 8; ++e) {
                float x = X1[(size_t)bir * 256 + c0 + e] + X2[(size_t)nrj * 256 + c0 + e] + eeb[c0 + e];
                v.u[e] = f2bf(fmaxf(x, 0.f));
            }
            *(short8*)&T[row * 512 + ((c0 * 2) ^ ((row & 7) << 4))] = v.s;
        }
    }
    __syncthreads();

    const int l = tid & 63, wv = tid >> 6, g = l >> 4, l15 = l & 15;
    f32x4 acc[4][4];
    zero_acc(acc);
    gemm_tile<8, 512>(T, WfA, acc, wv, l);
    __syncthreads();
#pragma unroll
    for (int ni = 0; ni < 4; ++ni) {
        int col = 64 * wv + 16 * ni + l15;
        float e1b = E1[(size_t)bir * 256 + col] + b1[col];
#pragma unroll
        for (int mi = 0; mi < 4; ++mi)
#pragma unroll
            for (int q = 0; q < 4; ++q) {
                int row = 16 * mi + 4 * g + q;
                float e2 = E2[(size_t)(b * 1024 + row * 16 + r) * 256 + col];
                float h = fmaxf(acc[mi][ni][q] + e1b + e2, 0.f);
                *(unsigned short*)&T[row * 512 + ((col * 2) ^ ((row & 7) << 4))] = f2bf(h);
                acc[mi][ni][q] = 0.f;
            }
    }
    __syncthreads();
    gemm_tile<8, 512>(T, WfB, acc, wv, l);
    // epilogue: eff = relu(acc + b2) -> LDS-image in HBM (swizzle baked in) + agg
    unsigned short* out16 = (unsigned short*)(img + (size_t)bir * 32768);
#pragma unroll
    for (int ni = 0; ni < 4; ++ni) {
        int col = 64 * wv + 16 * ni + l15;
        float bb = b2[col];
        float s = 0.f;
#pragma unroll
        for (int mi = 0; mi < 4; ++mi)
#pragma unroll
            for (int q = 0; q < 4; ++q) {
                int row = 16 * mi + 4 * g + q;
                float e = fmaxf(acc[mi][ni][q] + bb, 0.f);
                out16[(row * 512 + ((col * 2) ^ ((row & 7) << 4))) >> 1] = f2bf(e);
                s += e;
            }
        s += __shfl_xor(s, 16);
        s += __shfl_xor(s, 32);
        if (l < 16) agg[(size_t)bir * 256 + 64 * wv + 16 * ni + l] = s;
    }
}

// ---------------- fused edge step 1 + predictor (single 32KB tile) ----------------
__global__ __launch_bounds__(256, 4) void kstep2pred(const float* X1, const float* X2, const float* eeb,
        const float* E1, const float* E2, const float* b1, const float* b2,
        const unsigned short* WfA, const unsigned short* WfB,
        const unsigned short* WfPA, const unsigned short* WfPB, const unsigned short* WfP2,
        const float* prb1, const float* prb2,
        const unsigned char* img, float* out)
{
    __shared__ __align__(16) unsigned char T[64 * 512];
    const int bir = blockIdx.x, tid = threadIdx.x;
    const int b = bir >> 10, r = bir & 15;
    const int ebase = (bir >> 4) * 1024 + r;
    const int l = tid & 63, wv = tid >> 6, g = l >> 4, l15 = l & 15;

    // phase 0: async DMA eff image -> T (each wave stages 8 x 1KB chunks)
    {
        const unsigned char* src = img + (size_t)bir * 32768;
#pragma unroll
        for (int p = 0; p < 8; ++p) {
            int chunk = wv * 8 + p;
            dma16(src + chunk * 1024 + l * 16, &T[chunk * 1024]);
        }
    }
    __syncthreads();

    f32x4 acc[4][4];
    // h = relu(eff @ ep1W1c + E1 + E2 + b1) -> T
    zero_acc(acc);
    gemm_tile<8, 512>(T, WfA, acc, wv, l);
    __syncthreads();
#pragma unroll
    for (int ni = 0; ni < 4; ++ni) {
        int col = 64 * wv + 16 * ni + l15;
        float e1b = E1[(size_t)bir * 256 + col] + b1[col];
#pragma unroll
        for (int mi = 0; mi < 4; ++mi)
#pragma unroll
            for (int q = 0; q < 4; ++q) {
                int row = 16 * mi + 4 * g + q;
                float e2 = E2[(size_t)(b * 1024 + row * 16 + r) * 256 + col];
                float h = fmaxf(acc[mi][ni][q] + e1b + e2, 0.f);
                *(unsigned short*)&T[row * 512 + ((col * 2) ^ ((row & 7) << 4))] = f2bf(h);
                acc[mi][ni][q] = 0.f;
            }
    }
    __syncthreads();
    // eff2 = relu(h @ ep1W2 + b2) -> T
    gemm_tile<8, 512>(T, WfB, acc, wv, l);
    __syncthreads();
#pragma unroll
    for (int ni = 0; ni < 4; ++ni) {
        int col = 64 * wv + 16 * ni + l15;
        float bb = b2[col];
#pragma unroll
        for (int mi = 0; mi < 4; ++mi)
#pragma unroll
            for (int q = 0; q < 4; ++q) {
                int row = 16 * mi + 4 * g + q;
                *(unsigned short*)&T[row * 512 + ((col * 2) ^ ((row & 7) << 4))] =
                    f2bf(fmaxf(acc[mi][ni][q] + bb, 0.f));
            }
    }
    __syncthreads();
    // acc = eff2 @ prW1a
    zero_acc(acc);
    gemm_tile<8, 512>(T, WfPA, acc, wv, l);
    __syncthreads();
    // T <- e0 (recomputed; acc lives in regs across this)
    {
        int rlo = tid >> 5;
        int c0 = (tid & 31) * 8;
        for (int p = 0; p < 8; ++p) {
            int row = p * 8 + rlo;
            union { short8 s; unsigned short u[8]; } v;
            int nrj = b * 1024 + row * 16 + r;
#pragma unroll
            for (int e = 0; e < 8; ++e) {
                float x = X1[(size_t)bir * 256 + c0 + e] + X2[(size_t)nrj * 256 + c0 + e] + eeb[c0 + e];
                v.u[e] = f2bf(fmaxf(x, 0.f));
            }
            *(short8*)&T[row * 512 + ((c0 * 2) ^ ((row & 7) << 4))] = v.s;
        }
    }
    __syncthreads();
    // acc += e0 @ prW1b
    gemm_tile<8, 512>(T, WfPB, acc, wv, l);
    __syncthreads();
    // T <- p = relu(acc + prb1)
#pragma unroll
    for (int ni = 0; ni < 4; ++ni) {
        int col = 64 * wv + 16 * ni + l15;
        float pb = prb1[col];
#pragma unroll
        for (int mi = 0; mi < 4; ++mi)
#pragma unroll
            for (int q = 0; q < 4; ++q) {
                int row = 16 * mi + 4 * g + q;
                float p = fmaxf(acc[mi][ni][q] + pb, 0.f);
                *(unsigned short*)&T[row * 512 + ((col * 2) ^ ((row & 7) << 4))] = f2bf(p);
            }
    }
    __syncthreads();
    // out = p @ prW2 + prb2 : 64 cols, wave wv owns cols 16*wv..+15
    f32x4 acc3[4];
#pragma unroll
    for (int mi = 0; mi < 4; ++mi) acc3[mi] = (f32x4){0.f, 0.f, 0.f, 0.f};
    for (int kt = 0; kt < 8; ++kt) {
        short8 bf = *(const short8*)(WfP2 + (size_t)((kt * 4 + wv) * 64 + l) * 8);
#pragma unroll
        for (int mi = 0; mi < 4; ++mi) {
            short8 af = load_afrag<512>(T, 16 * mi + l15, kt, g);
            acc3[mi] = __builtin_amdgcn_mfma_f32_16x16x32_bf16(af, bf, acc3[mi], 0, 0, 0);
        }
    }
    int colo = 16 * wv + l15;
    float pb2 = prb2[colo];
#pragma unroll
    for (int mi = 0; mi < 4; ++mi)
#pragma unroll
        for (int q = 0; q < 4; ++q) {
            int row = 16 * mi + 4 * g + q;
            out[(size_t)(ebase + row * 16) * 64 + colo] = acc3[mi][q] + pb2;
        }
}

// ---------------- host ----------------
extern "C" void kernel_launch(void* const* d_in, const int* in_sizes, int n_in,
                              void* d_out, int out_size, void* d_ws, size_t ws_size,
                              hipStream_t stream)
{
    (void)in_sizes; (void)n_in; (void)out_size; (void)ws_size;
    const float* node_rep = (const float*)d_in[0];
    const float* neW   = (const float*)d_in[1];
    const float* neb   = (const float*)d_in[2];
    const float* eeW   = (const float*)d_in[3];
    const float* eeb   = (const float*)d_in[4];
    const float* npW1  = (const float*)d_in[5];
    const float* npb1  = (const float*)d_in[6];
    const float* npW2  = (const float*)d_in[7];
    const float* npb2  = (const float*)d_in[8];
    const float* ep0W1 = (const float*)d_in[9];
    const float* ep0b1 = (const float*)d_in[10];
    const float* ep0W2 = (const float*)d_in[11];
    const float* ep0b2 = (const float*)d_in[12];
    const float* ep1W1 = (const float*)d_in[13];
    const float* ep1b1 = (const float*)d_in[14];
    const float* ep1W2 = (const float*)d_in[15];
    const float* ep1b2 = (const float*)d_in[16];
    const float* prW1  = (const float*)d_in[17];
    const float* prb1  = (const float*)d_in[18];
    const float* prW2  = (const float*)d_in[19];
    const float* prb2  = (const float*)d_in[20];

    char* ws = (char*)d_ws;
    unsigned short* wsu = (unsigned short*)ws;
    auto wfull = [&](int i) { return (const unsigned short*)(ws + (size_t)i * WF_SZ); };
    unsigned short* node_enc = (unsigned short*)(ws + OFF_NENC);
    float* X1  = (float*)(ws + OFF_X1);
    float* X2  = (float*)(ws + OFF_X2);
    float* E1  = (float*)(ws + OFF_E1);
    float* E2  = (float*)(ws + OFF_E2);
    float* NE1 = (float*)(ws + OFF_NE1);
    float* agg = (float*)(ws + OFF_AGG);
    unsigned char* img = (unsigned char*)(ws + OFF_IMG);
    const unsigned short* neWf  = (const unsigned short*)(ws + OFF_NEW);
    const unsigned short* eeW1f = (const unsigned short*)(ws + OFF_EE1);
    const unsigned short* eeW2f = (const unsigned short*)(ws + OFF_EE2);
    const unsigned short* prW2f = (const unsigned short*)(ws + OFF_PW2);

    kconv<<<dim3(1920), dim3(64), 0, stream>>>(ep0W1, ep0W2, ep1W1, ep1W2, prW1, prW2,
                                               npW1, npW2, neW, eeW, wsu);
    knode12<<<dim3(32), dim3(256), 0, stream>>>(node_rep, neb, neWf, eeW1f, eeW2f,
                                                wfull(6), wfull(7), wfull(10),
                                                node_enc, X1, X2, E1, E2, NE1);
    kstep1<<<dim3(2048), dim3(256), 0, stream>>>(X1, X2, eeb, E1, E2, ep0b1, ep0b2,
                                                 wfull(0), wfull(1), img, agg);
    knode3<<<dim3(32), dim3(256), 0, stream>>>(node_enc, agg, NE1, npb1, npb2,
                                               wfull(8), wfull(9), wfull(11),
                                               wfull(12), wfull(13), E1, E2);
    kstep2pred<<<dim3(2048), dim3(256), 0, stream>>>(X1, X2, eeb, E1, E2, ep1b1, ep1b2,
                                                     wfull(2), wfull(3), wfull(4), wfull(5),
                                                     prW2f, prb1, prb2, img, (float*)d_out);
}

// Round 4
// 577.550 us; speedup vs baseline: 1.1413x; 1.1413x over previous
//
#include <hip/hip_runtime.h>
#include <hip/hip_bf16.h>

// PropNet fused MFMA-bf16 implementation for MI355X (gfx950).
// B=2 N=64 R=16 D=64 H=256 EOUT=64 PSTEP=2
// node rows nr = (b*64+i)*16 + r            (2048)
// edge rows er = ((b*64+i)*64 + j)*16 + r   (131072)
//
// R3 lesson: __launch_bounds__(256,4) (VGPR cap 128) forced spills ->
// 800 MB/dispatch scratch HBM traffic, 2x regression. Kernel needs ~152 VGPR;
// (256,3) caps at ~170 -> 3 blocks/CU (LDS 3x32KB=96<=160KB) with NO spills.
//
// Structure: single 32KB LDS tile time-multiplexed through the chain;
// eff passed between kstep1/kstep2pred as a per-tile 32KB "LDS image"
// (swizzle baked in), staged via async global_load_lds.
//
// All GEMMs: v_mfma_f32_16x16x32_bf16. Weights pre-packed into fragment order
// with the SAME (lane,elem)->k map as the LDS A-fragment reads, so any k-map
// mismatch vs HW cancels. LDS tiles XOR-swizzled: byte ^= (row&7)<<4.

typedef __attribute__((ext_vector_type(8))) short short8;
typedef __attribute__((ext_vector_type(4))) float f32x4;
typedef __attribute__((ext_vector_type(2))) unsigned int u32x2;

#define DI __device__ __forceinline__

// ---------------- workspace layout (bytes) ----------------
constexpr size_t WF_SZ = 131072;            // 256x256 bf16 frag matrix
// full 256x256 frag matrices, index:
// 0 ep0W1c(=ep0W1[512:768]) 1 ep0W2 2 ep1W1c 3 ep1W2 4 prW1a(=prW1[0:256])
// 5 prW1b(=prW1[256:512]) 6 E1w(=ep0W1[0:256]) 7 E2w(=ep0W1[256:512])
// 8 NE2w(=npW1[256:512]) 9 NAGGw(=npW1[512:768]) 10 NE1w(=npW1[0:256])
// 11 npW2 12 ep1Aw(=ep1W1[0:256]) 13 ep1Bw(=ep1W1[256:512])
constexpr size_t OFF_NEW  = 14 * WF_SZ;     // neW   64x256 frag (32 KB)
constexpr size_t OFF_EE1  = OFF_NEW + 32768; // eeW[0:64]
constexpr size_t OFF_EE2  = OFF_EE1 + 32768; // eeW[64:128]
constexpr size_t OFF_PW2  = OFF_EE2 + 32768; // prW2 256x64 frag
constexpr size_t OFF_NENC = OFF_PW2 + 32768; // node_enc bf16 [2048,256] 1MB
constexpr size_t OFF_X1   = OFF_NENC + (size_t)2048 * 256 * 2;
constexpr size_t SM = (size_t)2048 * 256 * 4;
constexpr size_t OFF_X2  = OFF_X1 + SM;
constexpr size_t OFF_E1  = OFF_X2 + SM;
constexpr size_t OFF_E2  = OFF_E1 + SM;
constexpr size_t OFF_NE1 = OFF_E2 + SM;
constexpr size_t OFF_AGG = OFF_NE1 + SM;
constexpr size_t OFF_IMG = OFF_AGG + SM;     // eff LDS-images: 2048 x 32KB = 64 MiB
// total ~79 MB

DI unsigned short f2bf(float f) {
    unsigned u = __builtin_bit_cast(unsigned, f);
    u += 0x7fffu + ((u >> 16) & 1u);
    return (unsigned short)(u >> 16);
}

// (lane-group g, element e) -> k offset within a 32-wide K tile.
DI int kmap(int g, int e) { return 4 * g + (e & 3) + ((e >> 2) << 4); }

// async 16B/lane global->LDS copy (wave-uniform LDS base, per-lane global src)
DI void dma16(const void* g, void* l) {
    __builtin_amdgcn_global_load_lds((const __attribute__((address_space(1))) void*)g,
                                     (__attribute__((address_space(3))) void*)l, 16, 0, 0);
}

// ---------------- weight repack: f32 [K x ld] -> bf16 fragment order ----------------
__global__ __launch_bounds__(64) void kconv(const float* ep0W1, const float* ep0W2,
                                            const float* ep1W1, const float* ep1W2,
                                            const float* prW1, const float* prW2,
                                            const float* npW1, const float* npW2,
                                            const float* neW, const float* eeW,
                                            unsigned short* wsu)
{
    int bid = blockIdx.x, l = threadIdx.x;
    const float* src; unsigned short* dst; int NT = 16, ld = 256, f;
    if (bid < 1792) {
        int m = bid >> 7; f = bid & 127;
        switch (m) {
            case 0:  src = ep0W1 + 512 * 256; break;
            case 1:  src = ep0W2;             break;
            case 2:  src = ep1W1 + 512 * 256; break;
            case 3:  src = ep1W2;             break;
            case 4:  src = prW1;              break;
            case 5:  src = prW1 + 256 * 256;  break;
            case 6:  src = ep0W1;             break;
            case 7:  src = ep0W1 + 256 * 256; break;
            case 8:  src = npW1 + 256 * 256;  break;
            case 9:  src = npW1 + 512 * 256;  break;
            case 10: src = npW1;              break;
            case 11: src = npW2;              break;
            case 12: src = ep1W1;             break;
            default: src = ep1W1 + 256 * 256; break;
        }
        dst = wsu + (size_t)m * (WF_SZ / 2);
    } else if (bid < 1888) {
        int m = (bid - 1792) >> 5; f = (bid - 1792) & 31;
        src = (m == 0) ? neW : (m == 1) ? eeW : eeW + 64 * 256;
        dst = wsu + ((m == 0) ? OFF_NEW : (m == 1) ? OFF_EE1 : OFF_EE2) / 2;
    } else {
        f = bid - 1888; NT = 4; ld = 64; src = prW2; dst = wsu + OFF_PW2 / 2;
    }
    int kt = f / NT, nt = f % NT;
    int g = l >> 4, c = nt * 16 + (l & 15);
    unsigned short* o = dst + (size_t)((kt * NT + nt) * 64 + l) * 8;
#pragma unroll
    for (int e = 0; e < 8; ++e) {
        int k = 32 * kt + kmap(g, e);
        o[e] = f2bf(src[(size_t)k * ld + c]);
    }
}

// ---------------- MFMA tile helpers ----------------
// LDS tile: rows x (LDB bytes), XOR swizzle byte ^= (row&7)<<4
template <int LDB>
DI short8 load_afrag(const unsigned char* lds, int row, int kt, int g) {
    int sw = (row & 7) << 4;
    int kb = 64 * kt + 8 * g;
    union { short8 s; u32x2 u[2]; } u_;
    u_.u[0] = *(const u32x2*)(lds + row * LDB + (kb ^ sw));
    u_.u[1] = *(const u32x2*)(lds + row * LDB + ((kb + 32) ^ sw));
    return u_.s;
}

DI void zero_acc(f32x4 (&acc)[4][4]) {
#pragma unroll
    for (int mi = 0; mi < 4; ++mi)
#pragma unroll
        for (int ni = 0; ni < 4; ++ni) acc[mi][ni] = (f32x4){0.f, 0.f, 0.f, 0.f};
}

// acc += Atile(64 x 32*KT, LDS) @ W(32*KT x 256, frag order); wave wv owns cols 64*wv..+63
template <int KT, int LDB>
DI void gemm_tile(const unsigned char* lds, const unsigned short* Wf,
                  f32x4 (&acc)[4][4], int wv, int l) {
    const int g = l >> 4, l15 = l & 15;
    for (int kt = 0; kt < KT; ++kt) {
        short8 af[4];
#pragma unroll
        for (int mi = 0; mi < 4; ++mi) af[mi] = load_afrag<LDB>(lds, 16 * mi + l15, kt, g);
        short8 bf[4];
#pragma unroll
        for (int ni = 0; ni < 4; ++ni)
            bf[ni] = *(const short8*)(Wf + (size_t)((kt * 16 + 4 * wv + ni) * 64 + l) * 8);
#pragma unroll
        for (int ni = 0; ni < 4; ++ni)
#pragma unroll
            for (int mi = 0; mi < 4; ++mi)
                acc[mi][ni] = __builtin_amdgcn_mfma_f32_16x16x32_bf16(af[mi], bf[ni], acc[mi][ni], 0, 0, 0);
    }
}

DI void store_tile_f32(float* dst, int r0, f32x4 (&acc)[4][4], int wv, int l) {
    int g = l >> 4, l15 = l & 15;
#pragma unroll
    for (int ni = 0; ni < 4; ++ni) {
        int col = 64 * wv + 16 * ni + l15;
#pragma unroll
        for (int mi = 0; mi < 4; ++mi)
#pragma unroll
            for (int q = 0; q < 4; ++q)
                dst[(size_t)(r0 + 16 * mi + 4 * g + q) * 256 + col] = acc[mi][ni][q];
    }
}

// ---------------- node path: encoder + edge-enc partials + E1/E2/NE1 ----------------
__global__ __launch_bounds__(256) void knode12(const float* node_rep, const float* neb,
        const unsigned short* neWf, const unsigned short* eeW1f, const unsigned short* eeW2f,
        const unsigned short* E1wf, const unsigned short* E2wf, const unsigned short* NE1wf,
        unsigned short* node_enc, float* X1, float* X2, float* E1, float* E2, float* NE1)
{
    __shared__ __align__(16) unsigned char ldsA[64 * 128];
    __shared__ __align__(16) unsigned char ldsB[64 * 512];
    const int r0 = blockIdx.x * 64, tid = threadIdx.x;
    {
        int row = tid >> 2, c0 = (tid & 3) * 16;
        const float* src = node_rep + (size_t)(r0 + row) * 64 + c0;
        union { short8 s; unsigned short u[8]; } v0, v1;
#pragma unroll
        for (int e = 0; e < 8; ++e) { v0.u[e] = f2bf(src[e]); v1.u[e] = f2bf(src[8 + e]); }
        int sw = (row & 7) << 4;
        *(short8*)&ldsA[row * 128 + ((c0 * 2) ^ sw)] = v0.s;
        *(short8*)&ldsA[row * 128 + ((c0 * 2 + 16) ^ sw)] = v1.s;
    }
    __syncthreads();
    const int l = tid & 63, wv = tid >> 6, g = l >> 4, l15 = l & 15;
    f32x4 acc[4][4];
    // node_enc = relu(node_rep @ neW + neb) -> bf16 ldsB + global
    zero_acc(acc);
    gemm_tile<2, 128>(ldsA, neWf, acc, wv, l);
#pragma unroll
    for (int ni = 0; ni < 4; ++ni) {
        int col = 64 * wv + 16 * ni + l15;
        float bb = neb[col];
#pragma unroll
        for (int mi = 0; mi < 4; ++mi)
#pragma unroll
            for (int q = 0; q < 4; ++q) {
                int row = 16 * mi + 4 * g + q;
                unsigned short bv = f2bf(fmaxf(acc[mi][ni][q] + bb, 0.f));
                *(unsigned short*)&ldsB[row * 512 + ((col * 2) ^ ((row & 7) << 4))] = bv;
                node_enc[(size_t)(r0 + row) * 256 + col] = bv;
            }
    }
    // X1 = node_rep @ eeW[:64], X2 = node_rep @ eeW[64:]
    zero_acc(acc);
    gemm_tile<2, 128>(ldsA, eeW1f, acc, wv, l);
    store_tile_f32(X1, r0, acc, wv, l);
    zero_acc(acc);
    gemm_tile<2, 128>(ldsA, eeW2f, acc, wv, l);
    store_tile_f32(X2, r0, acc, wv, l);
    __syncthreads();   // all ldsB writes done before K=256 gemms read it
    zero_acc(acc);
    gemm_tile<8, 512>(ldsB, E1wf, acc, wv, l);
    store_tile_f32(E1, r0, acc, wv, l);
    zero_acc(acc);
    gemm_tile<8, 512>(ldsB, E2wf, acc, wv, l);
    store_tile_f32(E2, r0, acc, wv, l);
    zero_acc(acc);
    gemm_tile<8, 512>(ldsB, NE1wf, acc, wv, l);
    store_tile_f32(NE1, r0, acc, wv, l);
}

// ---------------- node update chain (step-1) + E1_1/E2_1 ----------------
__global__ __launch_bounds__(256) void knode3(const unsigned short* node_enc, const float* agg,
        const float* NE1, const float* npb1, const float* npb2,
        const unsigned short* NE2wf, const unsigned short* NAGGwf, const unsigned short* npW2f,
        const unsigned short* ep1Awf, const unsigned short* ep1Bwf,
        float* E1, float* E2)
{
    __shared__ __align__(16) unsigned char ldsA[64 * 512];
    __shared__ __align__(16) unsigned char ldsB[64 * 512];
    const int r0 = blockIdx.x * 64, tid = threadIdx.x;
    {
        int row = tid >> 2, cbase = (tid & 3) * 64;
        int sw = (row & 7) << 4;
#pragma unroll
        for (int cc = 0; cc < 4; ++cc) {
            int c0 = cbase + cc * 16;
            short8 lo = *(const short8*)(node_enc + (size_t)(r0 + row) * 256 + c0);
            short8 hi = *(const short8*)(node_enc + (size_t)(r0 + row) * 256 + c0 + 8);
            *(short8*)&ldsA[row * 512 + ((c0 * 2) ^ sw)] = lo;
            *(short8*)&ldsA[row * 512 + ((c0 * 2 + 16) ^ sw)] = hi;
            union { short8 s; unsigned short u[8]; } v0, v1;
            const float* asrc = agg + (size_t)(r0 + row) * 256 + c0;
#pragma unroll
            for (int e = 0; e < 8; ++e) { v0.u[e] = f2bf(asrc[e]); v1.u[e] = f2bf(asrc[8 + e]); }
            *(short8*)&ldsB[row * 512 + ((c0 * 2) ^ sw)] = v0.s;
            *(short8*)&ldsB[row * 512 + ((c0 * 2 + 16) ^ sw)] = v1.s;
        }
    }
    __syncthreads();
    const int l = tid & 63, wv = tid >> 6, g = l >> 4, l15 = l & 15;
    f32x4 acc[4][4];
    // g = relu(NE1 + node_enc@NE2w + agg@NAGGw + npb1) -> bf16 ldsA
    zero_acc(acc);
    gemm_tile<8, 512>(ldsA, NE2wf, acc, wv, l);
    gemm_tile<8, 512>(ldsB, NAGGwf, acc, wv, l);
    __syncthreads();
#pragma unroll
    for (int ni = 0; ni < 4; ++ni) {
        int col = 64 * wv + 16 * ni + l15;
        float bb = npb1[col];
#pragma unroll
        for (int mi = 0; mi < 4; ++mi)
#pragma unroll
            for (int q = 0; q < 4; ++q) {
                int row = 16 * mi + 4 * g + q;
                float v = fmaxf(acc[mi][ni][q] + NE1[(size_t)(r0 + row) * 256 + col] + bb, 0.f);
                *(unsigned short*)&ldsA[row * 512 + ((col * 2) ^ ((row & 7) << 4))] = f2bf(v);
            }
    }
    __syncthreads();
    // nf = relu(g @ npW2 + npb2) -> bf16 ldsB
    zero_acc(acc);
    gemm_tile<8, 512>(ldsA, npW2f, acc, wv, l);
    __syncthreads();
#pragma unroll
    for (int ni = 0; ni < 4; ++ni) {
        int col = 64 * wv + 16 * ni + l15;
        float bb = npb2[col];
#pragma unroll
        for (int mi = 0; mi < 4; ++mi)
#pragma unroll
            for (int q = 0; q < 4; ++q) {
                int row = 16 * mi + 4 * g + q;
                *(unsigned short*)&ldsB[row * 512 + ((col * 2) ^ ((row & 7) << 4))] =
                    f2bf(fmaxf(acc[mi][ni][q] + bb, 0.f));
            }
    }
    __syncthreads();
    // E1 = nf @ ep1W1[0:256], E2 = nf @ ep1W1[256:512]
    zero_acc(acc);
    gemm_tile<8, 512>(ldsB, ep1Awf, acc, wv, l);
    store_tile_f32(E1, r0, acc, wv, l);
    zero_acc(acc);
    gemm_tile<8, 512>(ldsB, ep1Bwf, acc, wv, l);
    store_tile_f32(E2, r0, acc, wv, l);
}

// ---------------- fused edge propagation step 0 (writes eff-image + agg) ----------------
__global__ __launch_bounds__(256, 3) void kstep1(const float* X1, const float* X2, const float* eeb,
                                                 const float* E1, const float* E2,
                                                 const float* b1, const float* b2,
                                                 const unsigned short* WfA, const unsigned short* WfB,
                                                 unsigned char* img, float* agg)
{
    __shared__ __align__(16) unsigned char T[64 * 512];
    const int bir = blockIdx.x, tid = threadIdx.x;
    const int b = bir >> 10, r = bir & 15;

    {   // phase 0: build e0 tile (rows = senders j)
        int rlo = tid >> 5;
        int c0 = (tid & 31) * 8;
        for (int p = 0; p < 8; ++p) {
            int row = p * 8 + rlo;
            union { short8 s; unsigned short u[8]; } v;
            int nrj = b * 1024 + row * 16 + r;
#pragma unroll
            for (int e = 0; e < 8; ++e) {
                float x = X1[(size_t)bir * 256 + c0 + e] + X2[(size_t)nrj * 256 + c0 + e] + eeb[c0 + e];
                v.u[e] = f2bf(fmaxf(x, 0.f));
            }
            *(short8*)&T[row * 512 + ((c0 * 2) ^ ((row & 7) << 4))] = v.s;
        }
    }
    __syncthreads();

    const int l = tid & 63, wv = tid >> 6, g = l >> 4, l15 = l & 15;
    f32x4 acc[4][4];
    zero_acc(acc);
    gemm_tile<8, 512>(T, WfA, acc, wv, l);
    __syncthreads();
#pragma unroll
    for (int ni = 0; ni < 4; ++ni) {
        int col = 64 * wv + 16 * ni + l15;
        float e1b = E1[(size_t)bir * 256 + col] + b1[col];
#pragma unroll
        for (int mi = 0; mi < 4; ++mi)
#pragma unroll
            for (int q = 0; q < 4; ++q) {
                int row = 16 * mi + 4 * g + q;
                float e2 = E2[(size_t)(b * 1024 + row * 16 + r) * 256 + col];
                float h = fmaxf(acc[mi][ni][q] + e1b + e2, 0.f);
                *(unsigned short*)&T[row * 512 + ((col * 2) ^ ((row & 7) << 4))] = f2bf(h);
                acc[mi][ni][q] = 0.f;
            }
    }
    __syncthreads();
    gemm_tile<8, 512>(T, WfB, acc, wv, l);
    // epilogue: eff = relu(acc + b2) -> LDS-image in HBM (swizzle baked in) + agg
    unsigned short* out16 = (unsigned short*)(img + (size_t)bir * 32768);
#pragma unroll
    for (int ni = 0; ni < 4; ++ni) {
        int col = 64 * wv + 16 * ni + l15;
        float bb = b2[col];
        float s = 0.f;
#pragma unroll
        for (int mi = 0; mi < 4; ++mi)
#pragma unroll
            for (int q = 0; q < 4; ++q) {
                int row = 16 * mi + 4 * g + q;
                float e = fmaxf(acc[mi][ni][q] + bb, 0.f);
                out16[(row * 512 + ((col * 2) ^ ((row & 7) << 4))) >> 1] = f2bf(e);
                s += e;
            }
        s += __shfl_xor(s, 16);
        s += __shfl_xor(s, 32);
        if (l < 16) agg[(size_t)bir * 256 + 64 * wv + 16 * ni + l] = s;
    }
}

// ---------------- fused edge step 1 + predictor (single 32KB tile) ----------------
__global__ __launch_bounds__(256, 3) void kstep2pred(const float* X1, const float* X2, const float* eeb,
        const float* E1, const float* E2, const float* b1, const float* b2,
        const unsigned short* WfA, const unsigned short* WfB,
        const unsigned short* WfPA, const unsigned short* WfPB, const unsigned short* WfP2,
        const float* prb1, const float* prb2,
        const unsigned char* img, float* out)
{
    __shared__ __align__(16) unsigned char T[64 * 512];
    const int bir = blockIdx.x, tid = threadIdx.x;
    const int b = bir >> 10, r = bir & 15;
    const int ebase = (bir >> 4) * 1024 + r;
    const int l = tid & 63, wv = tid >> 6, g = l >> 4, l15 = l & 15;

    // phase 0: async DMA eff image -> T (each wave stages 8 x 1KB chunks)
    {
        const unsigned char* src = img + (size_t)bir * 32768;
#pragma unroll
        for (int p = 0; p < 8; ++p) {
            int chunk = wv * 8 + p;
            dma16(src + chunk * 1024 + l * 16, &T[chunk * 1024]);
        }
    }
    __syncthreads();

    f32x4 acc[4][4];
    // h = relu(eff @ ep1W1c + E1 + E2 + b1) -> T
    zero_acc(acc);
    gemm_tile<8, 512>(T, WfA, acc, wv, l);
    __syncthreads();
#pragma unroll
    for (int ni = 0; ni < 4; ++ni) {
        int col = 64 * wv + 16 * ni + l15;
        float e1b = E1[(size_t)bir * 256 + col] + b1[col];
#pragma unroll
        for (int mi = 0; mi < 4; ++mi)
#pragma unroll
            for (int q = 0; q < 4; ++q) {
                int row = 16 * mi + 4 * g + q;
                float e2 = E2[(size_t)(b * 1024 + row * 16 + r) * 256 + col];
                float h = fmaxf(acc[mi][ni][q] + e1b + e2, 0.f);
                *(unsigned short*)&T[row * 512 + ((col * 2) ^ ((row & 7) << 4))] = f2bf(h);
                acc[mi][ni][q] = 0.f;
            }
    }
    __syncthreads();
    // eff2 = relu(h @ ep1W2 + b2) -> T
    gemm_tile<8, 512>(T, WfB, acc, wv, l);
    __syncthreads();
#pragma unroll
    for (int ni = 0; ni < 4; ++ni) {
        int col = 64 * wv + 16 * ni + l15;
        float bb = b2[col];
#pragma unroll
        for (int mi = 0; mi < 4; ++mi)
#pragma unroll
            for (int q = 0; q < 4; ++q) {
                int row = 16 * mi + 4 * g + q;
                *(unsigned short*)&T[row * 512 + ((col * 2) ^ ((row & 7) << 4))] =
                    f2bf(fmaxf(acc[mi][ni][q] + bb, 0.f));
            }
    }
    __syncthreads();
    // acc = eff2 @ prW1a
    zero_acc(acc);
    gemm_tile<8, 512>(T, WfPA, acc, wv, l);
    __syncthreads();
    // T <- e0 (recomputed; acc lives in regs across this)
    {
        int rlo = tid >> 5;
        int c0 = (tid & 31) * 8;
        for (int p = 0; p < 8; ++p) {
            int row = p * 8 + rlo;
            union { short8 s; unsigned short u[8]; } v;
            int nrj = b * 1024 + row * 16 + r;
#pragma unroll
            for (int e = 0; e < 8; ++e) {
                float x = X1[(size_t)bir * 256 + c0 + e] + X2[(size_t)nrj * 256 + c0 + e] + eeb[c0 + e];
                v.u[e] = f2bf(fmaxf(x, 0.f));
            }
            *(short8*)&T[row * 512 + ((c0 * 2) ^ ((row & 7) << 4))] = v.s;
        }
    }
    __syncthreads();
    // acc += e0 @ prW1b
    gemm_tile<8, 512>(T, WfPB, acc, wv, l);
    __syncthreads();
    // T <- p = relu(acc + prb1)
#pragma unroll
    for (int ni = 0; ni < 4; ++ni) {
        int col = 64 * wv + 16 * ni + l15;
        float pb = prb1[col];
#pragma unroll
        for (int mi = 0; mi < 4; ++mi)
#pragma unroll
            for (int q = 0; q < 4; ++q) {
                int row = 16 * mi + 4 * g + q;
                float p = fmaxf(acc[mi][ni][q] + pb, 0.f);
                *(unsigned short*)&T[row * 512 + ((col * 2) ^ ((row & 7) << 4))] = f2bf(p);
            }
    }
    __syncthreads();
    // out = p @ prW2 + prb2 : 64 cols, wave wv owns cols 16*wv..+15
    f32x4 acc3[4];
#pragma unroll
    for (int mi = 0; mi < 4; ++mi) acc3[mi] = (f32x4){0.f, 0.f, 0.f, 0.f};
    for (int kt = 0; kt < 8; ++kt) {
        short8 bf = *(const short8*)(WfP2 + (size_t)((kt * 4 + wv) * 64 + l) * 8);
#pragma unroll
        for (int mi = 0; mi < 4; ++mi) {
            short8 af = load_afrag<512>(T, 16 * mi + l15, kt, g);
            acc3[mi] = __builtin_amdgcn_mfma_f32_16x16x32_bf16(af, bf, acc3[mi], 0, 0, 0);
        }
    }
    int colo = 16 * wv + l15;
    float pb2 = prb2[colo];
#pragma unroll
    for (int mi = 0; mi < 4; ++mi)
#pragma unroll
        for (int q = 0; q < 4; ++q) {
            int row = 16 * mi + 4 * g + q;
            out[(size_t)(ebase + row * 16) * 64 + colo] = acc3[mi][q] + pb2;
        }
}

// ---------------- host ----------------
extern "C" void kernel_launch(void* const* d_in, const int* in_sizes, int n_in,
                              void* d_out, int out_size, void* d_ws, size_t ws_size,
                              hipStream_t stream)
{
    (void)in_sizes; (void)n_in; (void)out_size; (void)ws_size;
    const float* node_rep = (const float*)d_in[0];
    const float* neW   = (const float*)d_in[1];
    const float* neb   = (const float*)d_in[2];
    const float* eeW   = (const float*)d_in[3];
    const float* eeb   = (const float*)d_in[4];
    const float* npW1  = (const float*)d_in[5];
    const float* npb1  = (const float*)d_in[6];
    const float* npW2  = (const float*)d_in[7];
    const float* npb2  = (const float*)d_in[8];
    const float* ep0W1 = (const float*)d_in[9];
    const float* ep0b1 = (const float*)d_in[10];
    const float* ep0W2 = (const float*)d_in[11];
    const float* ep0b2 = (const float*)d_in[12];
    const float* ep1W1 = (const float*)d_in[13];
    const float* ep1b1 = (const float*)d_in[14];
    const float* ep1W2 = (const float*)d_in[15];
    const float* ep1b2 = (const float*)d_in[16];
    const float* prW1  = (const float*)d_in[17];
    const float* prb1  = (const float*)d_in[18];
    const float* prW2  = (const float*)d_in[19];
    const float* prb2  = (const float*)d_in[20];

    char* ws = (char*)d_ws;
    unsigned short* wsu = (unsigned short*)ws;
    auto wfull = [&](int i) { return (const unsigned short*)(ws + (size_t)i * WF_SZ); };
    unsigned short* node_enc = (unsigned short*)(ws + OFF_NENC);
    float* X1  = (float*)(ws + OFF_X1);
    float* X2  = (float*)(ws + OFF_X2);
    float* E1  = (float*)(ws + OFF_E1);
    float* E2  = (float*)(ws + OFF_E2);
    float* NE1 = (float*)(ws + OFF_NE1);
    float* agg = (float*)(ws + OFF_AGG);
    unsigned char* img = (unsigned char*)(ws + OFF_IMG);
    const unsigned short* neWf  = (const unsigned short*)(ws + OFF_NEW);
    const unsigned short* eeW1f = (const unsigned short*)(ws + OFF_EE1);
    const unsigned short* eeW2f = (const unsigned short*)(ws + OFF_EE2);
    const unsigned short* prW2f = (const unsigned short*)(ws + OFF_PW2);

    kconv<<<dim3(1920), dim3(64), 0, stream>>>(ep0W1, ep0W2, ep1W1, ep1W2, prW1, prW2,
                                               npW1, npW2, neW, eeW, wsu);
    knode12<<<dim3(32), dim3(256), 0, stream>>>(node_rep, neb, neWf, eeW1f, eeW2f,
                                                wfull(6), wfull(7), wfull(10),
                                                node_enc, X1, X2, E1, E2, NE1);
    kstep1<<<dim3(2048), dim3(256), 0, stream>>>(X1, X2, eeb, E1, E2, ep0b1, ep0b2,
                                                 wfull(0), wfull(1), img, agg);
    knode3<<<dim3(32), dim3(256), 0, stream>>>(node_enc, agg, NE1, npb1, npb2,
                                               wfull(8), wfull(9), wfull(11),
                                               wfull(12), wfull(13), E1, E2);
    kstep2pred<<<dim3(2048), dim3(256), 0, stream>>>(X1, X2, eeb, E1, E2, ep1b1, ep1b2,
                                                     wfull(2), wfull(3), wfull(4), wfull(5),
                                                     prW2f, prb1, prb2, img, (float*)d_out);
}

// Round 5
// 475.790 us; speedup vs baseline: 1.3853x; 1.2139x over previous
//
#include <hip/hip_runtime.h>
#include <hip/hip_bf16.h>

// PropNet fused MFMA-bf16 implementation for MI355X (gfx950).
// B=2 N=64 R=16 D=64 H=256 EOUT=64 PSTEP=2
// node rows nr = (b*64+i)*16 + r            (2048)
// edge rows er = ((b*64+i)*64 + j)*16 + r   (131072)
//
// R4 lesson: hipcc maps __launch_bounds__(256,arg) to a VGPR cap of
// ~512/(2*arg) on gfx950 ((256,4)->64, (256,3)->84), NOT the "arg=blocks/CU"
// model. Kernel needs ~152 VGPR -> any cap below that spills to scratch
// (R3: 800MB, R4: 534MB HBM spill traffic/dispatch). Fix: NO min-waves arg.
// Natural allocation 152 VGPR -> 512/152 = 3 waves/SIMD = 3 blocks/CU,
// and the 32KB single-tile structure keeps LDS at 3x32=96KB <= 160KB.
//
// Structure: single 32KB LDS tile time-multiplexed through the chain;
// eff passed between kstep1/kstep2pred as a per-tile 32KB "LDS image"
// (swizzle baked in), staged via async global_load_lds.
//
// All GEMMs: v_mfma_f32_16x16x32_bf16. Weights pre-packed into fragment order
// with the SAME (lane,elem)->k map as the LDS A-fragment reads, so any k-map
// mismatch vs HW cancels. LDS tiles XOR-swizzled: byte ^= (row&7)<<4.

typedef __attribute__((ext_vector_type(8))) short short8;
typedef __attribute__((ext_vector_type(4))) float f32x4;
typedef __attribute__((ext_vector_type(2))) unsigned int u32x2;

#define DI __device__ __forceinline__

// ---------------- workspace layout (bytes) ----------------
constexpr size_t WF_SZ = 131072;            // 256x256 bf16 frag matrix
// full 256x256 frag matrices, index:
// 0 ep0W1c(=ep0W1[512:768]) 1 ep0W2 2 ep1W1c 3 ep1W2 4 prW1a(=prW1[0:256])
// 5 prW1b(=prW1[256:512]) 6 E1w(=ep0W1[0:256]) 7 E2w(=ep0W1[256:512])
// 8 NE2w(=npW1[256:512]) 9 NAGGw(=npW1[512:768]) 10 NE1w(=npW1[0:256])
// 11 npW2 12 ep1Aw(=ep1W1[0:256]) 13 ep1Bw(=ep1W1[256:512])
constexpr size_t OFF_NEW  = 14 * WF_SZ;     // neW   64x256 frag (32 KB)
constexpr size_t OFF_EE1  = OFF_NEW + 32768; // eeW[0:64]
constexpr size_t OFF_EE2  = OFF_EE1 + 32768; // eeW[64:128]
constexpr size_t OFF_PW2  = OFF_EE2 + 32768; // prW2 256x64 frag
constexpr size_t OFF_NENC = OFF_PW2 + 32768; // node_enc bf16 [2048,256] 1MB
constexpr size_t OFF_X1   = OFF_NENC + (size_t)2048 * 256 * 2;
constexpr size_t SM = (size_t)2048 * 256 * 4;
constexpr size_t OFF_X2  = OFF_X1 + SM;
constexpr size_t OFF_E1  = OFF_X2 + SM;
constexpr size_t OFF_E2  = OFF_E1 + SM;
constexpr size_t OFF_NE1 = OFF_E2 + SM;
constexpr size_t OFF_AGG = OFF_NE1 + SM;
constexpr size_t OFF_IMG = OFF_AGG + SM;     // eff LDS-images: 2048 x 32KB = 64 MiB
// total ~79 MB

DI unsigned short f2bf(float f) {
    unsigned u = __builtin_bit_cast(unsigned, f);
    u += 0x7fffu + ((u >> 16) & 1u);
    return (unsigned short)(u >> 16);
}

// (lane-group g, element e) -> k offset within a 32-wide K tile.
DI int kmap(int g, int e) { return 4 * g + (e & 3) + ((e >> 2) << 4); }

// async 16B/lane global->LDS copy (wave-uniform LDS base, per-lane global src)
DI void dma16(const void* g, void* l) {
    __builtin_amdgcn_global_load_lds((const __attribute__((address_space(1))) void*)g,
                                     (__attribute__((address_space(3))) void*)l, 16, 0, 0);
}

// ---------------- weight repack: f32 [K x ld] -> bf16 fragment order ----------------
__global__ __launch_bounds__(64) void kconv(const float* ep0W1, const float* ep0W2,
                                            const float* ep1W1, const float* ep1W2,
                                            const float* prW1, const float* prW2,
                                            const float* npW1, const float* npW2,
                                            const float* neW, const float* eeW,
                                            unsigned short* wsu)
{
    int bid = blockIdx.x, l = threadIdx.x;
    const float* src; unsigned short* dst; int NT = 16, ld = 256, f;
    if (bid < 1792) {
        int m = bid >> 7; f = bid & 127;
        switch (m) {
            case 0:  src = ep0W1 + 512 * 256; break;
            case 1:  src = ep0W2;             break;
            case 2:  src = ep1W1 + 512 * 256; break;
            case 3:  src = ep1W2;             break;
            case 4:  src = prW1;              break;
            case 5:  src = prW1 + 256 * 256;  break;
            case 6:  src = ep0W1;             break;
            case 7:  src = ep0W1 + 256 * 256; break;
            case 8:  src = npW1 + 256 * 256;  break;
            case 9:  src = npW1 + 512 * 256;  break;
            case 10: src = npW1;              break;
            case 11: src = npW2;              break;
            case 12: src = ep1W1;             break;
            default: src = ep1W1 + 256 * 256; break;
        }
        dst = wsu + (size_t)m * (WF_SZ / 2);
    } else if (bid < 1888) {
        int m = (bid - 1792) >> 5; f = (bid - 1792) & 31;
        src = (m == 0) ? neW : (m == 1) ? eeW : eeW + 64 * 256;
        dst = wsu + ((m == 0) ? OFF_NEW : (m == 1) ? OFF_EE1 : OFF_EE2) / 2;
    } else {
        f = bid - 1888; NT = 4; ld = 64; src = prW2; dst = wsu + OFF_PW2 / 2;
    }
    int kt = f / NT, nt = f % NT;
    int g = l >> 4, c = nt * 16 + (l & 15);
    unsigned short* o = dst + (size_t)((kt * NT + nt) * 64 + l) * 8;
#pragma unroll
    for (int e = 0; e < 8; ++e) {
        int k = 32 * kt + kmap(g, e);
        o[e] = f2bf(src[(size_t)k * ld + c]);
    }
}

// ---------------- MFMA tile helpers ----------------
// LDS tile: rows x (LDB bytes), XOR swizzle byte ^= (row&7)<<4
template <int LDB>
DI short8 load_afrag(const unsigned char* lds, int row, int kt, int g) {
    int sw = (row & 7) << 4;
    int kb = 64 * kt + 8 * g;
    union { short8 s; u32x2 u[2]; } u_;
    u_.u[0] = *(const u32x2*)(lds + row * LDB + (kb ^ sw));
    u_.u[1] = *(const u32x2*)(lds + row * LDB + ((kb + 32) ^ sw));
    return u_.s;
}

DI void zero_acc(f32x4 (&acc)[4][4]) {
#pragma unroll
    for (int mi = 0; mi < 4; ++mi)
#pragma unroll
        for (int ni = 0; ni < 4; ++ni) acc[mi][ni] = (f32x4){0.f, 0.f, 0.f, 0.f};
}

// acc += Atile(64 x 32*KT, LDS) @ W(32*KT x 256, frag order); wave wv owns cols 64*wv..+63
template <int KT, int LDB>
DI void gemm_tile(const unsigned char* lds, const unsigned short* Wf,
                  f32x4 (&acc)[4][4], int wv, int l) {
    const int g = l >> 4, l15 = l & 15;
    for (int kt = 0; kt < KT; ++kt) {
        short8 af[4];
#pragma unroll
        for (int mi = 0; mi < 4; ++mi) af[mi] = load_afrag<LDB>(lds, 16 * mi + l15, kt, g);
        short8 bf[4];
#pragma unroll
        for (int ni = 0; ni < 4; ++ni)
            bf[ni] = *(const short8*)(Wf + (size_t)((kt * 16 + 4 * wv + ni) * 64 + l) * 8);
#pragma unroll
        for (int ni = 0; ni < 4; ++ni)
#pragma unroll
            for (int mi = 0; mi < 4; ++mi)
                acc[mi][ni] = __builtin_amdgcn_mfma_f32_16x16x32_bf16(af[mi], bf[ni], acc[mi][ni], 0, 0, 0);
    }
}

DI void store_tile_f32(float* dst, int r0, f32x4 (&acc)[4][4], int wv, int l) {
    int g = l >> 4, l15 = l & 15;
#pragma unroll
    for (int ni = 0; ni < 4; ++ni) {
        int col = 64 * wv + 16 * ni + l15;
#pragma unroll
        for (int mi = 0; mi < 4; ++mi)
#pragma unroll
            for (int q = 0; q < 4; ++q)
                dst[(size_t)(r0 + 16 * mi + 4 * g + q) * 256 + col] = acc[mi][ni][q];
    }
}

// ---------------- node path: encoder + edge-enc partials + E1/E2/NE1 ----------------
__global__ __launch_bounds__(256) void knode12(const float* node_rep, const float* neb,
        const unsigned short* neWf, const unsigned short* eeW1f, const unsigned short* eeW2f,
        const unsigned short* E1wf, const unsigned short* E2wf, const unsigned short* NE1wf,
        unsigned short* node_enc, float* X1, float* X2, float* E1, float* E2, float* NE1)
{
    __shared__ __align__(16) unsigned char ldsA[64 * 128];
    __shared__ __align__(16) unsigned char ldsB[64 * 512];
    const int r0 = blockIdx.x * 64, tid = threadIdx.x;
    {
        int row = tid >> 2, c0 = (tid & 3) * 16;
        const float* src = node_rep + (size_t)(r0 + row) * 64 + c0;
        union { short8 s; unsigned short u[8]; } v0, v1;
#pragma unroll
        for (int e = 0; e < 8; ++e) { v0.u[e] = f2bf(src[e]); v1.u[e] = f2bf(src[8 + e]); }
        int sw = (row & 7) << 4;
        *(short8*)&ldsA[row * 128 + ((c0 * 2) ^ sw)] = v0.s;
        *(short8*)&ldsA[row * 128 + ((c0 * 2 + 16) ^ sw)] = v1.s;
    }
    __syncthreads();
    const int l = tid & 63, wv = tid >> 6, g = l >> 4, l15 = l & 15;
    f32x4 acc[4][4];
    // node_enc = relu(node_rep @ neW + neb) -> bf16 ldsB + global
    zero_acc(acc);
    gemm_tile<2, 128>(ldsA, neWf, acc, wv, l);
#pragma unroll
    for (int ni = 0; ni < 4; ++ni) {
        int col = 64 * wv + 16 * ni + l15;
        float bb = neb[col];
#pragma unroll
        for (int mi = 0; mi < 4; ++mi)
#pragma unroll
            for (int q = 0; q < 4; ++q) {
                int row = 16 * mi + 4 * g + q;
                unsigned short bv = f2bf(fmaxf(acc[mi][ni][q] + bb, 0.f));
                *(unsigned short*)&ldsB[row * 512 + ((col * 2) ^ ((row & 7) << 4))] = bv;
                node_enc[(size_t)(r0 + row) * 256 + col] = bv;
            }
    }
    // X1 = node_rep @ eeW[:64], X2 = node_rep @ eeW[64:]
    zero_acc(acc);
    gemm_tile<2, 128>(ldsA, eeW1f, acc, wv, l);
    store_tile_f32(X1, r0, acc, wv, l);
    zero_acc(acc);
    gemm_tile<2, 128>(ldsA, eeW2f, acc, wv, l);
    store_tile_f32(X2, r0, acc, wv, l);
    __syncthreads();   // all ldsB writes done before K=256 gemms read it
    zero_acc(acc);
    gemm_tile<8, 512>(ldsB, E1wf, acc, wv, l);
    store_tile_f32(E1, r0, acc, wv, l);
    zero_acc(acc);
    gemm_tile<8, 512>(ldsB, E2wf, acc, wv, l);
    store_tile_f32(E2, r0, acc, wv, l);
    zero_acc(acc);
    gemm_tile<8, 512>(ldsB, NE1wf, acc, wv, l);
    store_tile_f32(NE1, r0, acc, wv, l);
}

// ---------------- node update chain (step-1) + E1_1/E2_1 ----------------
__global__ __launch_bounds__(256) void knode3(const unsigned short* node_enc, const float* agg,
        const float* NE1, const float* npb1, const float* npb2,
        const unsigned short* NE2wf, const unsigned short* NAGGwf, const unsigned short* npW2f,
        const unsigned short* ep1Awf, const unsigned short* ep1Bwf,
        float* E1, float* E2)
{
    __shared__ __align__(16) unsigned char ldsA[64 * 512];
    __shared__ __align__(16) unsigned char ldsB[64 * 512];
    const int r0 = blockIdx.x * 64, tid = threadIdx.x;
    {
        int row = tid >> 2, cbase = (tid & 3) * 64;
        int sw = (row & 7) << 4;
#pragma unroll
        for (int cc = 0; cc < 4; ++cc) {
            int c0 = cbase + cc * 16;
            short8 lo = *(const short8*)(node_enc + (size_t)(r0 + row) * 256 + c0);
            short8 hi = *(const short8*)(node_enc + (size_t)(r0 + row) * 256 + c0 + 8);
            *(short8*)&ldsA[row * 512 + ((c0 * 2) ^ sw)] = lo;
            *(short8*)&ldsA[row * 512 + ((c0 * 2 + 16) ^ sw)] = hi;
            union { short8 s; unsigned short u[8]; } v0, v1;
            const float* asrc = agg + (size_t)(r0 + row) * 256 + c0;
#pragma unroll
            for (int e = 0; e < 8; ++e) { v0.u[e] = f2bf(asrc[e]); v1.u[e] = f2bf(asrc[8 + e]); }
            *(short8*)&ldsB[row * 512 + ((c0 * 2) ^ sw)] = v0.s;
            *(short8*)&ldsB[row * 512 + ((c0 * 2 + 16) ^ sw)] = v1.s;
        }
    }
    __syncthreads();
    const int l = tid & 63, wv = tid >> 6, g = l >> 4, l15 = l & 15;
    f32x4 acc[4][4];
    // g = relu(NE1 + node_enc@NE2w + agg@NAGGw + npb1) -> bf16 ldsA
    zero_acc(acc);
    gemm_tile<8, 512>(ldsA, NE2wf, acc, wv, l);
    gemm_tile<8, 512>(ldsB, NAGGwf, acc, wv, l);
    __syncthreads();
#pragma unroll
    for (int ni = 0; ni < 4; ++ni) {
        int col = 64 * wv + 16 * ni + l15;
        float bb = npb1[col];
#pragma unroll
        for (int mi = 0; mi < 4; ++mi)
#pragma unroll
            for (int q = 0; q < 4; ++q) {
                int row = 16 * mi + 4 * g + q;
                float v = fmaxf(acc[mi][ni][q] + NE1[(size_t)(r0 + row) * 256 + col] + bb, 0.f);
                *(unsigned short*)&ldsA[row * 512 + ((col * 2) ^ ((row & 7) << 4))] = f2bf(v);
            }
    }
    __syncthreads();
    // nf = relu(g @ npW2 + npb2) -> bf16 ldsB
    zero_acc(acc);
    gemm_tile<8, 512>(ldsA, npW2f, acc, wv, l);
    __syncthreads();
#pragma unroll
    for (int ni = 0; ni < 4; ++ni) {
        int col = 64 * wv + 16 * ni + l15;
        float bb = npb2[col];
#pragma unroll
        for (int mi = 0; mi < 4; ++mi)
#pragma unroll
            for (int q = 0; q < 4; ++q) {
                int row = 16 * mi + 4 * g + q;
                *(unsigned short*)&ldsB[row * 512 + ((col * 2) ^ ((row & 7) << 4))] =
                    f2bf(fmaxf(acc[mi][ni][q] + bb, 0.f));
            }
    }
    __syncthreads();
    // E1 = nf @ ep1W1[0:256], E2 = nf @ ep1W1[256:512]
    zero_acc(acc);
    gemm_tile<8, 512>(ldsB, ep1Awf, acc, wv, l);
    store_tile_f32(E1, r0, acc, wv, l);
    zero_acc(acc);
    gemm_tile<8, 512>(ldsB, ep1Bwf, acc, wv, l);
    store_tile_f32(E2, r0, acc, wv, l);
}

// ---------------- fused edge propagation step 0 (writes eff-image + agg) ----------------
__global__ __launch_bounds__(256) void kstep1(const float* X1, const float* X2, const float* eeb,
                                              const float* E1, const float* E2,
                                              const float* b1, const float* b2,
                                              const unsigned short* WfA, const unsigned short* WfB,
                                              unsigned char* img, float* agg)
{
    __shared__ __align__(16) unsigned char T[64 * 512];
    const int bir = blockIdx.x, tid = threadIdx.x;
    const int b = bir >> 10, r = bir & 15;

    {   // phase 0: build e0 tile (rows = senders j)
        int rlo = tid >> 5;
        int c0 = (tid & 31) * 8;
        for (int p = 0; p < 8; ++p) {
            int row = p * 8 + rlo;
            union { short8 s; unsigned short u[8]; } v;
            int nrj = b * 1024 + row * 16 + r;
#pragma unroll
            for (int e = 0; e < 8; ++e) {
                float x = X1[(size_t)bir * 256 + c0 + e] + X2[(size_t)nrj * 256 + c0 + e] + eeb[c0 + e];
                v.u[e] = f2bf(fmaxf(x, 0.f));
            }
            *(short8*)&T[row * 512 + ((c0 * 2) ^ ((row & 7) << 4))] = v.s;
        }
    }
    __syncthreads();

    const int l = tid & 63, wv = tid >> 6, g = l >> 4, l15 = l & 15;
    f32x4 acc[4][4];
    zero_acc(acc);
    gemm_tile<8, 512>(T, WfA, acc, wv, l);
    __syncthreads();
#pragma unroll
    for (int ni = 0; ni < 4; ++ni) {
        int col = 64 * wv + 16 * ni + l15;
        float e1b = E1[(size_t)bir * 256 + col] + b1[col];
#pragma unroll
        for (int mi = 0; mi < 4; ++mi)
#pragma unroll
            for (int q = 0; q < 4; ++q) {
                int row = 16 * mi + 4 * g + q;
                float e2 = E2[(size_t)(b * 1024 + row * 16 + r) * 256 + col];
                float h = fmaxf(acc[mi][ni][q] + e1b + e2, 0.f);
                *(unsigned short*)&T[row * 512 + ((col * 2) ^ ((row & 7) << 4))] = f2bf(h);
                acc[mi][ni][q] = 0.f;
            }
    }
    __syncthreads();
    gemm_tile<8, 512>(T, WfB, acc, wv, l);
    // epilogue: eff = relu(acc + b2) -> LDS-image in HBM (swizzle baked in) + agg
    unsigned short* out16 = (unsigned short*)(img + (size_t)bir * 32768);
#pragma unroll
    for (int ni = 0; ni < 4; ++ni) {
        int col = 64 * wv + 16 * ni + l15;
        float bb = b2[col];
        float s = 0.f;
#pragma unroll
        for (int mi = 0; mi < 4; ++mi)
#pragma unroll
            for (int q = 0; q < 4; ++q) {
                int row = 16 * mi + 4 * g + q;
                float e = fmaxf(acc[mi][ni][q] + bb, 0.f);
                out16[(row * 512 + ((col * 2) ^ ((row & 7) << 4))) >> 1] = f2bf(e);
                s += e;
            }
        s += __shfl_xor(s, 16);
        s += __shfl_xor(s, 32);
        if (l < 16) agg[(size_t)bir * 256 + 64 * wv + 16 * ni + l] = s;
    }
}

// ---------------- fused edge step 1 + predictor (single 32KB tile) ----------------
__global__ __launch_bounds__(256) void kstep2pred(const float* X1, const float* X2, const float* eeb,
        const float* E1, const float* E2, const float* b1, const float* b2,
        const unsigned short* WfA, const unsigned short* WfB,
        const unsigned short* WfPA, const unsigned short* WfPB, const unsigned short* WfP2,
        const float* prb1, const float* prb2,
        const unsigned char* img, float* out)
{
    __shared__ __align__(16) unsigned char T[64 * 512];
    const int bir = blockIdx.x, tid = threadIdx.x;
    const int b = bir >> 10, r = bir & 15;
    const int ebase = (bir >> 4) * 1024 + r;
    const int l = tid & 63, wv = tid >> 6, g = l >> 4, l15 = l & 15;

    // phase 0: async DMA eff image -> T (each wave stages 8 x 1KB chunks)
    {
        const unsigned char* src = img + (size_t)bir * 32768;
#pragma unroll
        for (int p = 0; p < 8; ++p) {
            int chunk = wv * 8 + p;
            dma16(src + chunk * 1024 + l * 16, &T[chunk * 1024]);
        }
    }
    __syncthreads();

    f32x4 acc[4][4];
    // h = relu(eff @ ep1W1c + E1 + E2 + b1) -> T
    zero_acc(acc);
    gemm_tile<8, 512>(T, WfA, acc, wv, l);
    __syncthreads();
#pragma unroll
    for (int ni = 0; ni < 4; ++ni) {
        int col = 64 * wv + 16 * ni + l15;
        float e1b = E1[(size_t)bir * 256 + col] + b1[col];
#pragma unroll
        for (int mi = 0; mi < 4; ++mi)
#pragma unroll
            for (int q = 0; q < 4; ++q) {
                int row = 16 * mi + 4 * g + q;
                float e2 = E2[(size_t)(b * 1024 + row * 16 + r) * 256 + col];
                float h = fmaxf(acc[mi][ni][q] + e1b + e2, 0.f);
                *(unsigned short*)&T[row * 512 + ((col * 2) ^ ((row & 7) << 4))] = f2bf(h);
                acc[mi][ni][q] = 0.f;
            }
    }
    __syncthreads();
    // eff2 = relu(h @ ep1W2 + b2) -> T
    gemm_tile<8, 512>(T, WfB, acc, wv, l);
    __syncthreads();
#pragma unroll
    for (int ni = 0; ni < 4; ++ni) {
        int col = 64 * wv + 16 * ni + l15;
        float bb = b2[col];
#pragma unroll
        for (int mi = 0; mi < 4; ++mi)
#pragma unroll
            for (int q = 0; q < 4; ++q) {
                int row = 16 * mi + 4 * g + q;
                *(unsigned short*)&T[row * 512 + ((col * 2) ^ ((row & 7) << 4))] =
                    f2bf(fmaxf(acc[mi][ni][q] + bb, 0.f));
            }
    }
    __syncthreads();
    // acc = eff2 @ prW1a
    zero_acc(acc);
    gemm_tile<8, 512>(T, WfPA, acc, wv, l);
    __syncthreads();
    // T <- e0 (recomputed; acc lives in regs across this)
    {
        int rlo = tid >> 5;
        int c0 = (tid & 31) * 8;
        for (int p = 0; p < 8; ++p) {
            int row = p * 8 + rlo;
            union { short8 s; unsigned short u[8]; } v;
            int nrj = b * 1024 + row * 16 + r;
#pragma unroll
            for (int e = 0; e < 8; ++e) {
                float x = X1[(size_t)bir * 256 + c0 + e] + X2[(size_t)nrj * 256 + c0 + e] + eeb[c0 + e];
                v.u[e] = f2bf(fmaxf(x, 0.f));
            }
            *(short8*)&T[row * 512 + ((c0 * 2) ^ ((row & 7) << 4))] = v.s;
        }
    }
    __syncthreads();
    // acc += e0 @ prW1b
    gemm_tile<8, 512>(T, WfPB, acc, wv, l);
    __syncthreads();
    // T <- p = relu(acc + prb1)
#pragma unroll
    for (int ni = 0; ni < 4; ++ni) {
        int col = 64 * wv + 16 * ni + l15;
        float pb = prb1[col];
#pragma unroll
        for (int mi = 0; mi < 4; ++mi)
#pragma unroll
            for (int q = 0; q < 4; ++q) {
                int row = 16 * mi + 4 * g + q;
                float p = fmaxf(acc[mi][ni][q] + pb, 0.f);
                *(unsigned short*)&T[row * 512 + ((col * 2) ^ ((row & 7) << 4))] = f2bf(p);
            }
    }
    __syncthreads();
    // out = p @ prW2 + prb2 : 64 cols, wave wv owns cols 16*wv..+15
    f32x4 acc3[4];
#pragma unroll
    for (int mi = 0; mi < 4; ++mi) acc3[mi] = (f32x4){0.f, 0.f, 0.f, 0.f};
    for (int kt = 0; kt < 8; ++kt) {
        short8 bf = *(const short8*)(WfP2 + (size_t)((kt * 4 + wv) * 64 + l) * 8);
#pragma unroll
        for (int mi = 0; mi < 4; ++mi) {
            short8 af = load_afrag<512>(T, 16 * mi + l15, kt, g);
            acc3[mi] = __builtin_amdgcn_mfma_f32_16x16x32_bf16(af, bf, acc3[mi], 0, 0, 0);
        }
    }
    int colo = 16 * wv + l15;
    float pb2 = prb2[colo];
#pragma unroll
    for (int mi = 0; mi < 4; ++mi)
#pragma unroll
        for (int q = 0; q < 4; ++q) {
            int row = 16 * mi + 4 * g + q;
            out[(size_t)(ebase + row * 16) * 64 + colo] = acc3[mi][q] + pb2;
        }
}

// ---------------- host ----------------
extern "C" void kernel_launch(void* const* d_in, const int* in_sizes, int n_in,
                              void* d_out, int out_size, void* d_ws, size_t ws_size,
                              hipStream_t stream)
{
    (void)in_sizes; (void)n_in; (void)out_size; (void)ws_size;
    const float* node_rep = (const float*)d_in[0];
    const float* neW   = (const float*)d_in[1];
    const float* neb   = (const float*)d_in[2];
    const float* eeW   = (const float*)d_in[3];
    const float* eeb   = (const float*)d_in[4];
    const float* npW1  = (const float*)d_in[5];
    const float* npb1  = (const float*)d_in[6];
    const float* npW2  = (const float*)d_in[7];
    const float* npb2  = (const float*)d_in[8];
    const float* ep0W1 = (const float*)d_in[9];
    const float* ep0b1 = (const float*)d_in[10];
    const float* ep0W2 = (const float*)d_in[11];
    const float* ep0b2 = (const float*)d_in[12];
    const float* ep1W1 = (const float*)d_in[13];
    const float* ep1b1 = (const float*)d_in[14];
    const float* ep1W2 = (const float*)d_in[15];
    const float* ep1b2 = (const float*)d_in[16];
    const float* prW1  = (const float*)d_in[17];
    const float* prb1  = (const float*)d_in[18];
    const float* prW2  = (const float*)d_in[19];
    const float* prb2  = (const float*)d_in[20];

    char* ws = (char*)d_ws;
    unsigned short* wsu = (unsigned short*)ws;
    auto wfull = [&](int i) { return (const unsigned short*)(ws + (size_t)i * WF_SZ); };
    unsigned short* node_enc = (unsigned short*)(ws + OFF_NENC);
    float* X1  = (float*)(ws + OFF_X1);
    float* X2  = (float*)(ws + OFF_X2);
    float* E1  = (float*)(ws + OFF_E1);
    float* E2  = (float*)(ws + OFF_E2);
    float* NE1 = (float*)(ws + OFF_NE1);
    float* agg = (float*)(ws + OFF_AGG);
    unsigned char* img = (unsigned char*)(ws + OFF_IMG);
    const unsigned short* neWf  = (const unsigned short*)(ws + OFF_NEW);
    const unsigned short* eeW1f = (const unsigned short*)(ws + OFF_EE1);
    const unsigned short* eeW2f = (const unsigned short*)(ws + OFF_EE2);
    const unsigned short* prW2f = (const unsigned short*)(ws + OFF_PW2);

    kconv<<<dim3(1920), dim3(64), 0, stream>>>(ep0W1, ep0W2, ep1W1, ep1W2, prW1, prW2,
                                               npW1, npW2, neW, eeW, wsu);
    knode12<<<dim3(32), dim3(256), 0, stream>>>(node_rep, neb, neWf, eeW1f, eeW2f,
                                                wfull(6), wfull(7), wfull(10),
                                                node_enc, X1, X2, E1, E2, NE1);
    kstep1<<<dim3(2048), dim3(256), 0, stream>>>(X1, X2, eeb, E1, E2, ep0b1, ep0b2,
                                                 wfull(0), wfull(1), img, agg);
    knode3<<<dim3(32), dim3(256), 0, stream>>>(node_enc, agg, NE1, npb1, npb2,
                                               wfull(8), wfull(9), wfull(11),
                                               wfull(12), wfull(13), E1, E2);
    kstep2pred<<<dim3(2048), dim3(256), 0, stream>>>(X1, X2, eeb, E1, E2, ep1b1, ep1b2,
                                                     wfull(2), wfull(3), wfull(4), wfull(5),
                                                     prW2f, prb1, prb2, img, (float*)d_out);
}

// Round 6
// 381.813 us; speedup vs baseline: 1.7263x; 1.2461x over previous
//
#include <hip/hip_runtime.h>
#include <hip/hip_bf16.h>

// PropNet fused MFMA-bf16 implementation for MI355X (gfx950).
// B=2 N=64 R=16 D=64 H=256 EOUT=64 PSTEP=2
// node rows nr = (b*64+i)*16 + r            (2048)
// edge rows er = ((b*64+i)*64 + j)*16 + r   (131072)
//
// R5 lesson: with acc[4][4] (64 VGPR) natural alloc is 150-180 VGPR ->
// only 2 waves/SIMD, MfmaUtil stuck at 15%. Occupancy can only rise if the
// per-wave accumulator shrinks. R6: edge tiles split 64->32 rows (4096
// blocks), acc[2][4]=32 VGPR, ~100 live -> __launch_bounds__(256,2)
// (empirical cap model 512/(2*arg) -> 128) -> 4 waves/SIMD, no spills.
// agg is written as 2 half-partials (no atomics); knode3 sums them.
// eff image is 16KB per half-tile (same 64MB total), DMA-staged.
//
// All GEMMs: v_mfma_f32_16x16x32_bf16. Weights pre-packed into fragment order
// with the SAME (lane,elem)->k map as the LDS A-fragment reads, so any k-map
// mismatch vs HW cancels. LDS tiles XOR-swizzled: byte ^= (row&7)<<4.

typedef __attribute__((ext_vector_type(8))) short short8;
typedef __attribute__((ext_vector_type(4))) float f32x4;
typedef __attribute__((ext_vector_type(2))) unsigned int u32x2;

#define DI __device__ __forceinline__

// ---------------- workspace layout (bytes) ----------------
constexpr size_t WF_SZ = 131072;            // 256x256 bf16 frag matrix
// full 256x256 frag matrices, index:
// 0 ep0W1c(=ep0W1[512:768]) 1 ep0W2 2 ep1W1c 3 ep1W2 4 prW1a(=prW1[0:256])
// 5 prW1b(=prW1[256:512]) 6 E1w(=ep0W1[0:256]) 7 E2w(=ep0W1[256:512])
// 8 NE2w(=npW1[256:512]) 9 NAGGw(=npW1[512:768]) 10 NE1w(=npW1[0:256])
// 11 npW2 12 ep1Aw(=ep1W1[0:256]) 13 ep1Bw(=ep1W1[256:512])
constexpr size_t OFF_NEW  = 14 * WF_SZ;     // neW   64x256 frag (32 KB)
constexpr size_t OFF_EE1  = OFF_NEW + 32768; // eeW[0:64]
constexpr size_t OFF_EE2  = OFF_EE1 + 32768; // eeW[64:128]
constexpr size_t OFF_PW2  = OFF_EE2 + 32768; // prW2 256x64 frag
constexpr size_t OFF_NENC = OFF_PW2 + 32768; // node_enc bf16 [2048,256] 1MB
constexpr size_t OFF_X1   = OFF_NENC + (size_t)2048 * 256 * 2;
constexpr size_t SM = (size_t)2048 * 256 * 4;
constexpr size_t OFF_X2  = OFF_X1 + SM;
constexpr size_t OFF_E1  = OFF_X2 + SM;
constexpr size_t OFF_E2  = OFF_E1 + SM;
constexpr size_t OFF_NE1 = OFF_E2 + SM;
constexpr size_t OFF_AGG = OFF_NE1 + SM;     // 2 halves: 2 x 2MB
constexpr size_t OFF_IMG = OFF_AGG + 2 * SM; // eff images: 4096 x 16KB = 64 MiB
// total ~81 MB

DI unsigned short f2bf(float f) {
    unsigned u = __builtin_bit_cast(unsigned, f);
    u += 0x7fffu + ((u >> 16) & 1u);
    return (unsigned short)(u >> 16);
}

// (lane-group g, element e) -> k offset within a 32-wide K tile.
DI int kmap(int g, int e) { return 4 * g + (e & 3) + ((e >> 2) << 4); }

// async 16B/lane global->LDS copy (wave-uniform LDS base, per-lane global src)
DI void dma16(const void* g, void* l) {
    __builtin_amdgcn_global_load_lds((const __attribute__((address_space(1))) void*)g,
                                     (__attribute__((address_space(3))) void*)l, 16, 0, 0);
}

// ---------------- weight repack: f32 [K x ld] -> bf16 fragment order ----------------
__global__ __launch_bounds__(64) void kconv(const float* ep0W1, const float* ep0W2,
                                            const float* ep1W1, const float* ep1W2,
                                            const float* prW1, const float* prW2,
                                            const float* npW1, const float* npW2,
                                            const float* neW, const float* eeW,
                                            unsigned short* wsu)
{
    int bid = blockIdx.x, l = threadIdx.x;
    const float* src; unsigned short* dst; int NT = 16, ld = 256, f;
    if (bid < 1792) {
        int m = bid >> 7; f = bid & 127;
        switch (m) {
            case 0:  src = ep0W1 + 512 * 256; break;
            case 1:  src = ep0W2;             break;
            case 2:  src = ep1W1 + 512 * 256; break;
            case 3:  src = ep1W2;             break;
            case 4:  src = prW1;              break;
            case 5:  src = prW1 + 256 * 256;  break;
            case 6:  src = ep0W1;             break;
            case 7:  src = ep0W1 + 256 * 256; break;
            case 8:  src = npW1 + 256 * 256;  break;
            case 9:  src = npW1 + 512 * 256;  break;
            case 10: src = npW1;              break;
            case 11: src = npW2;              break;
            case 12: src = ep1W1;             break;
            default: src = ep1W1 + 256 * 256; break;
        }
        dst = wsu + (size_t)m * (WF_SZ / 2);
    } else if (bid < 1888) {
        int m = (bid - 1792) >> 5; f = (bid - 1792) & 31;
        src = (m == 0) ? neW : (m == 1) ? eeW : eeW + 64 * 256;
        dst = wsu + ((m == 0) ? OFF_NEW : (m == 1) ? OFF_EE1 : OFF_EE2) / 2;
    } else {
        f = bid - 1888; NT = 4; ld = 64; src = prW2; dst = wsu + OFF_PW2 / 2;
    }
    int kt = f / NT, nt = f % NT;
    int g = l >> 4, c = nt * 16 + (l & 15);
    unsigned short* o = dst + (size_t)((kt * NT + nt) * 64 + l) * 8;
#pragma unroll
    for (int e = 0; e < 8; ++e) {
        int k = 32 * kt + kmap(g, e);
        o[e] = f2bf(src[(size_t)k * ld + c]);
    }
}

// ---------------- MFMA tile helpers ----------------
// LDS tile: rows x (LDB bytes), XOR swizzle byte ^= (row&7)<<4
template <int LDB>
DI short8 load_afrag(const unsigned char* lds, int row, int kt, int g) {
    int sw = (row & 7) << 4;
    int kb = 64 * kt + 8 * g;
    union { short8 s; u32x2 u[2]; } u_;
    u_.u[0] = *(const u32x2*)(lds + row * LDB + (kb ^ sw));
    u_.u[1] = *(const u32x2*)(lds + row * LDB + ((kb + 32) ^ sw));
    return u_.s;
}

template <int MI>
DI void zero_acc(f32x4 (&acc)[MI][4]) {
#pragma unroll
    for (int mi = 0; mi < MI; ++mi)
#pragma unroll
        for (int ni = 0; ni < 4; ++ni) acc[mi][ni] = (f32x4){0.f, 0.f, 0.f, 0.f};
}

// acc += Atile(16*MI x 32*KT, LDS) @ W(32*KT x 256, frag order); wave wv owns cols 64*wv..+63
template <int MI, int KT, int LDB>
DI void gemm_tile(const unsigned char* lds, const unsigned short* Wf,
                  f32x4 (&acc)[MI][4], int wv, int l) {
    const int g = l >> 4, l15 = l & 15;
    for (int kt = 0; kt < KT; ++kt) {
        short8 af[MI];
#pragma unroll
        for (int mi = 0; mi < MI; ++mi) af[mi] = load_afrag<LDB>(lds, 16 * mi + l15, kt, g);
        short8 bf[4];
#pragma unroll
        for (int ni = 0; ni < 4; ++ni)
            bf[ni] = *(const short8*)(Wf + (size_t)((kt * 16 + 4 * wv + ni) * 64 + l) * 8);
#pragma unroll
        for (int ni = 0; ni < 4; ++ni)
#pragma unroll
            for (int mi = 0; mi < MI; ++mi)
                acc[mi][ni] = __builtin_amdgcn_mfma_f32_16x16x32_bf16(af[mi], bf[ni], acc[mi][ni], 0, 0, 0);
    }
}

DI void store_tile_f32(float* dst, int r0, f32x4 (&acc)[4][4], int wv, int l) {
    int g = l >> 4, l15 = l & 15;
#pragma unroll
    for (int ni = 0; ni < 4; ++ni) {
        int col = 64 * wv + 16 * ni + l15;
#pragma unroll
        for (int mi = 0; mi < 4; ++mi)
#pragma unroll
            for (int q = 0; q < 4; ++q)
                dst[(size_t)(r0 + 16 * mi + 4 * g + q) * 256 + col] = acc[mi][ni][q];
    }
}

// ---------------- node path: encoder + edge-enc partials + E1/E2/NE1 ----------------
__global__ __launch_bounds__(256) void knode12(const float* node_rep, const float* neb,
        const unsigned short* neWf, const unsigned short* eeW1f, const unsigned short* eeW2f,
        const unsigned short* E1wf, const unsigned short* E2wf, const unsigned short* NE1wf,
        unsigned short* node_enc, float* X1, float* X2, float* E1, float* E2, float* NE1)
{
    __shared__ __align__(16) unsigned char ldsA[64 * 128];
    __shared__ __align__(16) unsigned char ldsB[64 * 512];
    const int r0 = blockIdx.x * 64, tid = threadIdx.x;
    {
        int row = tid >> 2, c0 = (tid & 3) * 16;
        const float* src = node_rep + (size_t)(r0 + row) * 64 + c0;
        union { short8 s; unsigned short u[8]; } v0, v1;
#pragma unroll
        for (int e = 0; e < 8; ++e) { v0.u[e] = f2bf(src[e]); v1.u[e] = f2bf(src[8 + e]); }
        int sw = (row & 7) << 4;
        *(short8*)&ldsA[row * 128 + ((c0 * 2) ^ sw)] = v0.s;
        *(short8*)&ldsA[row * 128 + ((c0 * 2 + 16) ^ sw)] = v1.s;
    }
    __syncthreads();
    const int l = tid & 63, wv = tid >> 6, g = l >> 4, l15 = l & 15;
    f32x4 acc[4][4];
    // node_enc = relu(node_rep @ neW + neb) -> bf16 ldsB + global
    zero_acc(acc);
    gemm_tile<4, 2, 128>(ldsA, neWf, acc, wv, l);
#pragma unroll
    for (int ni = 0; ni < 4; ++ni) {
        int col = 64 * wv + 16 * ni + l15;
        float bb = neb[col];
#pragma unroll
        for (int mi = 0; mi < 4; ++mi)
#pragma unroll
            for (int q = 0; q < 4; ++q) {
                int row = 16 * mi + 4 * g + q;
                unsigned short bv = f2bf(fmaxf(acc[mi][ni][q] + bb, 0.f));
                *(unsigned short*)&ldsB[row * 512 + ((col * 2) ^ ((row & 7) << 4))] = bv;
                node_enc[(size_t)(r0 + row) * 256 + col] = bv;
            }
    }
    // X1 = node_rep @ eeW[:64], X2 = node_rep @ eeW[64:]
    zero_acc(acc);
    gemm_tile<4, 2, 128>(ldsA, eeW1f, acc, wv, l);
    store_tile_f32(X1, r0, acc, wv, l);
    zero_acc(acc);
    gemm_tile<4, 2, 128>(ldsA, eeW2f, acc, wv, l);
    store_tile_f32(X2, r0, acc, wv, l);
    __syncthreads();   // all ldsB writes done before K=256 gemms read it
    zero_acc(acc);
    gemm_tile<4, 8, 512>(ldsB, E1wf, acc, wv, l);
    store_tile_f32(E1, r0, acc, wv, l);
    zero_acc(acc);
    gemm_tile<4, 8, 512>(ldsB, E2wf, acc, wv, l);
    store_tile_f32(E2, r0, acc, wv, l);
    zero_acc(acc);
    gemm_tile<4, 8, 512>(ldsB, NE1wf, acc, wv, l);
    store_tile_f32(NE1, r0, acc, wv, l);
}

// ---------------- node update chain (step-1) + E1_1/E2_1 ----------------
__global__ __launch_bounds__(256) void knode3(const unsigned short* node_enc, const float* agg,
        const float* NE1, const float* npb1, const float* npb2,
        const unsigned short* NE2wf, const unsigned short* NAGGwf, const unsigned short* npW2f,
        const unsigned short* ep1Awf, const unsigned short* ep1Bwf,
        float* E1, float* E2)
{
    __shared__ __align__(16) unsigned char ldsA[64 * 512];
    __shared__ __align__(16) unsigned char ldsB[64 * 512];
    const int r0 = blockIdx.x * 64, tid = threadIdx.x;
    {
        int row = tid >> 2, cbase = (tid & 3) * 64;
        int sw = (row & 7) << 4;
#pragma unroll
        for (int cc = 0; cc < 4; ++cc) {
            int c0 = cbase + cc * 16;
            short8 lo = *(const short8*)(node_enc + (size_t)(r0 + row) * 256 + c0);
            short8 hi = *(const short8*)(node_enc + (size_t)(r0 + row) * 256 + c0 + 8);
            *(short8*)&ldsA[row * 512 + ((c0 * 2) ^ sw)] = lo;
            *(short8*)&ldsA[row * 512 + ((c0 * 2 + 16) ^ sw)] = hi;
            union { short8 s; unsigned short u[8]; } v0, v1;
            const float* aA = agg + (size_t)(r0 + row) * 256 + c0;
            const float* aB = aA + (size_t)2048 * 256;   // second half-partial
#pragma unroll
            for (int e = 0; e < 8; ++e) {
                v0.u[e] = f2bf(aA[e] + aB[e]);
                v1.u[e] = f2bf(aA[8 + e] + aB[8 + e]);
            }
            *(short8*)&ldsB[row * 512 + ((c0 * 2) ^ sw)] = v0.s;
            *(short8*)&ldsB[row * 512 + ((c0 * 2 + 16) ^ sw)] = v1.s;
        }
    }
    __syncthreads();
    const int l = tid & 63, wv = tid >> 6, g = l >> 4, l15 = l & 15;
    f32x4 acc[4][4];
    // g = relu(NE1 + node_enc@NE2w + agg@NAGGw + npb1) -> bf16 ldsA
    zero_acc(acc);
    gemm_tile<4, 8, 512>(ldsA, NE2wf, acc, wv, l);
    gemm_tile<4, 8, 512>(ldsB, NAGGwf, acc, wv, l);
    __syncthreads();
#pragma unroll
    for (int ni = 0; ni < 4; ++ni) {
        int col = 64 * wv + 16 * ni + l15;
        float bb = npb1[col];
#pragma unroll
        for (int mi = 0; mi < 4; ++mi)
#pragma unroll
            for (int q = 0; q < 4; ++q) {
                int row = 16 * mi + 4 * g + q;
                float v = fmaxf(acc[mi][ni][q] + NE1[(size_t)(r0 + row) * 256 + col] + bb, 0.f);
                *(unsigned short*)&ldsA[row * 512 + ((col * 2) ^ ((row & 7) << 4))] = f2bf(v);
            }
    }
    __syncthreads();
    // nf = relu(g @ npW2 + npb2) -> bf16 ldsB
    zero_acc(acc);
    gemm_tile<4, 8, 512>(ldsA, npW2f, acc, wv, l);
    __syncthreads();
#pragma unroll
    for (int ni = 0; ni < 4; ++ni) {
        int col = 64 * wv + 16 * ni + l15;
        float bb = npb2[col];
#pragma unroll
        for (int mi = 0; mi < 4; ++mi)
#pragma unroll
            for (int q = 0; q < 4; ++q) {
                int row = 16 * mi + 4 * g + q;
                *(unsigned short*)&ldsB[row * 512 + ((col * 2) ^ ((row & 7) << 4))] =
                    f2bf(fmaxf(acc[mi][ni][q] + bb, 0.f));
            }
    }
    __syncthreads();
    // E1 = nf @ ep1W1[0:256], E2 = nf @ ep1W1[256:512]
    zero_acc(acc);
    gemm_tile<4, 8, 512>(ldsB, ep1Awf, acc, wv, l);
    store_tile_f32(E1, r0, acc, wv, l);
    zero_acc(acc);
    gemm_tile<4, 8, 512>(ldsB, ep1Bwf, acc, wv, l);
    store_tile_f32(E2, r0, acc, wv, l);
}

// ---------------- fused edge propagation step 0, 32-row half-tiles ----------------
__global__ __launch_bounds__(256, 2) void kstep1(const float* X1, const float* X2, const float* eeb,
                                                 const float* E1, const float* E2,
                                                 const float* b1, const float* b2,
                                                 const unsigned short* WfA, const unsigned short* WfB,
                                                 unsigned char* img, float* agg)
{
    __shared__ __align__(16) unsigned char T[32 * 512];
    const int bb = blockIdx.x, tid = threadIdx.x;
    const int bir = bb >> 1, half = bb & 1;
    const int b = bir >> 10, r = bir & 15;

    {   // phase 0: build e0 half-tile (rows = senders j = half*32 + row)
        int rlo = tid >> 5;
        int c0 = (tid & 31) * 8;
        for (int p = 0; p < 4; ++p) {
            int row = p * 8 + rlo;
            union { short8 s; unsigned short u[8]; } v;
            int nrj = b * 1024 + (half * 32 + row) * 16 + r;
#pragma unroll
            for (int e = 0; e < 8; ++e) {
                float x = X1[(size_t)bir * 256 + c0 + e] + X2[(size_t)nrj * 256 + c0 + e] + eeb[c0 + e];
                v.u[e] = f2bf(fmaxf(x, 0.f));
            }
            *(short8*)&T[row * 512 + ((c0 * 2) ^ ((row & 7) << 4))] = v.s;
        }
    }
    __syncthreads();

    const int l = tid & 63, wv = tid >> 6, g = l >> 4, l15 = l & 15;
    f32x4 acc[2][4];
    zero_acc(acc);
    gemm_tile<2, 8, 512>(T, WfA, acc, wv, l);
    __syncthreads();
#pragma unroll
    for (int ni = 0; ni < 4; ++ni) {
        int col = 64 * wv + 16 * ni + l15;
        float e1b = E1[(size_t)bir * 256 + col] + b1[col];
#pragma unroll
        for (int mi = 0; mi < 2; ++mi)
#pragma unroll
            for (int q = 0; q < 4; ++q) {
                int row = 16 * mi + 4 * g + q;
                float e2 = E2[(size_t)(b * 1024 + (half * 32 + row) * 16 + r) * 256 + col];
                float h = fmaxf(acc[mi][ni][q] + e1b + e2, 0.f);
                *(unsigned short*)&T[row * 512 + ((col * 2) ^ ((row & 7) << 4))] = f2bf(h);
                acc[mi][ni][q] = 0.f;
            }
    }
    __syncthreads();
    gemm_tile<2, 8, 512>(T, WfB, acc, wv, l);
    // epilogue: eff = relu(acc + b2) -> 16KB LDS-image in HBM + agg half-partial
    unsigned short* out16 = (unsigned short*)(img + (size_t)bb * 16384);
#pragma unroll
    for (int ni = 0; ni < 4; ++ni) {
        int col = 64 * wv + 16 * ni + l15;
        float bb2 = b2[col];
        float s = 0.f;
#pragma unroll
        for (int mi = 0; mi < 2; ++mi)
#pragma unroll
            for (int q = 0; q < 4; ++q) {
                int row = 16 * mi + 4 * g + q;
                float e = fmaxf(acc[mi][ni][q] + bb2, 0.f);
                out16[(row * 512 + ((col * 2) ^ ((row & 7) << 4))) >> 1] = f2bf(e);
                s += e;
            }
        s += __shfl_xor(s, 16);
        s += __shfl_xor(s, 32);
        if (l < 16) agg[((size_t)half * 2048 + bir) * 256 + 64 * wv + 16 * ni + l] = s;
    }
}

// ---------------- fused edge step 1 + predictor, 32-row half-tiles ----------------
__global__ __launch_bounds__(256, 2) void kstep2pred(const float* X1, const float* X2, const float* eeb,
        const float* E1, const float* E2, const float* b1, const float* b2,
        const unsigned short* WfA, const unsigned short* WfB,
        const unsigned short* WfPA, const unsigned short* WfPB, const unsigned short* WfP2,
        const float* prb1, const float* prb2,
        const unsigned char* img, float* out)
{
    __shared__ __align__(16) unsigned char T[32 * 512];
    const int bb = blockIdx.x, tid = threadIdx.x;
    const int bir = bb >> 1, half = bb & 1;
    const int b = bir >> 10, r = bir & 15;
    const int ebase = (bir >> 4) * 1024 + r;
    const int l = tid & 63, wv = tid >> 6, g = l >> 4, l15 = l & 15;

    // phase 0: async DMA eff image -> T (each wave stages 4 x 1KB chunks)
    {
        const unsigned char* src = img + (size_t)bb * 16384;
#pragma unroll
        for (int p = 0; p < 4; ++p) {
            int chunk = wv * 4 + p;
            dma16(src + chunk * 1024 + l * 16, &T[chunk * 1024]);
        }
    }
    __syncthreads();

    f32x4 acc[2][4];
    // h = relu(eff @ ep1W1c + E1 + E2 + b1) -> T
    zero_acc(acc);
    gemm_tile<2, 8, 512>(T, WfA, acc, wv, l);
    __syncthreads();
#pragma unroll
    for (int ni = 0; ni < 4; ++ni) {
        int col = 64 * wv + 16 * ni + l15;
        float e1b = E1[(size_t)bir * 256 + col] + b1[col];
#pragma unroll
        for (int mi = 0; mi < 2; ++mi)
#pragma unroll
            for (int q = 0; q < 4; ++q) {
                int row = 16 * mi + 4 * g + q;
                float e2 = E2[(size_t)(b * 1024 + (half * 32 + row) * 16 + r) * 256 + col];
                float h = fmaxf(acc[mi][ni][q] + e1b + e2, 0.f);
                *(unsigned short*)&T[row * 512 + ((col * 2) ^ ((row & 7) << 4))] = f2bf(h);
                acc[mi][ni][q] = 0.f;
            }
    }
    __syncthreads();
    // eff2 = relu(h @ ep1W2 + b2) -> T
    gemm_tile<2, 8, 512>(T, WfB, acc, wv, l);
    __syncthreads();
#pragma unroll
    for (int ni = 0; ni < 4; ++ni) {
        int col = 64 * wv + 16 * ni + l15;
        float bb2 = b2[col];
#pragma unroll
        for (int mi = 0; mi < 2; ++mi)
#pragma unroll
            for (int q = 0; q < 4; ++q) {
                int row = 16 * mi + 4 * g + q;
                *(unsigned short*)&T[row * 512 + ((col * 2) ^ ((row & 7) << 4))] =
                    f2bf(fmaxf(acc[mi][ni][q] + bb2, 0.f));
            }
    }
    __syncthreads();
    // acc = eff2 @ prW1a
    zero_acc(acc);
    gemm_tile<2, 8, 512>(T, WfPA, acc, wv, l);
    __syncthreads();
    // T <- e0 (recomputed; acc lives in regs across this)
    {
        int rlo = tid >> 5;
        int c0 = (tid & 31) * 8;
        for (int p = 0; p < 4; ++p) {
            int row = p * 8 + rlo;
            union { short8 s; unsigned short u[8]; } v;
            int nrj = b * 1024 + (half * 32 + row) * 16 + r;
#pragma unroll
            for (int e = 0; e < 8; ++e) {
                float x = X1[(size_t)bir * 256 + c0 + e] + X2[(size_t)nrj * 256 + c0 + e] + eeb[c0 + e];
                v.u[e] = f2bf(fmaxf(x, 0.f));
            }
            *(short8*)&T[row * 512 + ((c0 * 2) ^ ((row & 7) << 4))] = v.s;
        }
    }
    __syncthreads();
    // acc += e0 @ prW1b
    gemm_tile<2, 8, 512>(T, WfPB, acc, wv, l);
    __syncthreads();
    // T <- p = relu(acc + prb1)
#pragma unroll
    for (int ni = 0; ni < 4; ++ni) {
        int col = 64 * wv + 16 * ni + l15;
        float pb = prb1[col];
#pragma unroll
        for (int mi = 0; mi < 2; ++mi)
#pragma unroll
            for (int q = 0; q < 4; ++q) {
                int row = 16 * mi + 4 * g + q;
                float p = fmaxf(acc[mi][ni][q] + pb, 0.f);
                *(unsigned short*)&T[row * 512 + ((col * 2) ^ ((row & 7) << 4))] = f2bf(p);
            }
    }
    __syncthreads();
    // out = p @ prW2 + prb2 : 64 cols, wave wv owns cols 16*wv..+15
    f32x4 acc3[2];
#pragma unroll
    for (int mi = 0; mi < 2; ++mi) acc3[mi] = (f32x4){0.f, 0.f, 0.f, 0.f};
    for (int kt = 0; kt < 8; ++kt) {
        short8 bf = *(const short8*)(WfP2 + (size_t)((kt * 4 + wv) * 64 + l) * 8);
#pragma unroll
        for (int mi = 0; mi < 2; ++mi) {
            short8 af = load_afrag<512>(T, 16 * mi + l15, kt, g);
            acc3[mi] = __builtin_amdgcn_mfma_f32_16x16x32_bf16(af, bf, acc3[mi], 0, 0, 0);
        }
    }
    int colo = 16 * wv + l15;
    float pb2 = prb2[colo];
#pragma unroll
    for (int mi = 0; mi < 2; ++mi)
#pragma unroll
        for (int q = 0; q < 4; ++q) {
            int row = 16 * mi + 4 * g + q;
            out[(size_t)(ebase + (half * 32 + row) * 16) * 64 + colo] = acc3[mi][q] + pb2;
        }
}

// ---------------- host ----------------
extern "C" void kernel_launch(void* const* d_in, const int* in_sizes, int n_in,
                              void* d_out, int out_size, void* d_ws, size_t ws_size,
                              hipStream_t stream)
{
    (void)in_sizes; (void)n_in; (void)out_size; (void)ws_size;
    const float* node_rep = (const float*)d_in[0];
    const float* neW   = (const float*)d_in[1];
    const float* neb   = (const float*)d_in[2];
    const float* eeW   = (const float*)d_in[3];
    const float* eeb   = (const float*)d_in[4];
    const float* npW1  = (const float*)d_in[5];
    const float* npb1  = (const float*)d_in[6];
    const float* npW2  = (const float*)d_in[7];
    const float* npb2  = (const float*)d_in[8];
    const float* ep0W1 = (const float*)d_in[9];
    const float* ep0b1 = (const float*)d_in[10];
    const float* ep0W2 = (const float*)d_in[11];
    const float* ep0b2 = (const float*)d_in[12];
    const float* ep1W1 = (const float*)d_in[13];
    const float* ep1b1 = (const float*)d_in[14];
    const float* ep1W2 = (const float*)d_in[15];
    const float* ep1b2 = (const float*)d_in[16];
    const float* prW1  = (const float*)d_in[17];
    const float* prb1  = (const float*)d_in[18];
    const float* prW2  = (const float*)d_in[19];
    const float* prb2  = (const float*)d_in[20];

    char* ws = (char*)d_ws;
    unsigned short* wsu = (unsigned short*)ws;
    auto wfull = [&](int i) { return (const unsigned short*)(ws + (size_t)i * WF_SZ); };
    unsigned short* node_enc = (unsigned short*)(ws + OFF_NENC);
    float* X1  = (float*)(ws + OFF_X1);
    float* X2  = (float*)(ws + OFF_X2);
    float* E1  = (float*)(ws + OFF_E1);
    float* E2  = (float*)(ws + OFF_E2);
    float* NE1 = (float*)(ws + OFF_NE1);
    float* agg = (float*)(ws + OFF_AGG);
    unsigned char* img = (unsigned char*)(ws + OFF_IMG);
    const unsigned short* neWf  = (const unsigned short*)(ws + OFF_NEW);
    const unsigned short* eeW1f = (const unsigned short*)(ws + OFF_EE1);
    const unsigned short* eeW2f = (const unsigned short*)(ws + OFF_EE2);
    const unsigned short* prW2f = (const unsigned short*)(ws + OFF_PW2);

    kconv<<<dim3(1920), dim3(64), 0, stream>>>(ep0W1, ep0W2, ep1W1, ep1W2, prW1, prW2,
                                               npW1, npW2, neW, eeW, wsu);
    knode12<<<dim3(32), dim3(256), 0, stream>>>(node_rep, neb, neWf, eeW1f, eeW2f,
                                                wfull(6), wfull(7), wfull(10),
                                                node_enc, X1, X2, E1, E2, NE1);
    kstep1<<<dim3(4096), dim3(256), 0, stream>>>(X1, X2, eeb, E1, E2, ep0b1, ep0b2,
                                                 wfull(0), wfull(1), img, agg);
    knode3<<<dim3(32), dim3(256), 0, stream>>>(node_enc, agg, NE1, npb1, npb2,
                                               wfull(8), wfull(9), wfull(11),
                                               wfull(12), wfull(13), E1, E2);
    kstep2pred<<<dim3(4096), dim3(256), 0, stream>>>(X1, X2, eeb, E1, E2, ep1b1, ep1b2,
                                                     wfull(2), wfull(3), wfull(4), wfull(5),
                                                     prW2f, prb1, prb2, img, (float*)d_out);
}

// Round 7
// 344.524 us; speedup vs baseline: 1.9132x; 1.1082x over previous
//
#include <hip/hip_runtime.h>
#include <hip/hip_bf16.h>

// PropNet fused MFMA-bf16 implementation for MI355X (gfx950).
// B=2 N=64 R=16 D=64 H=256 EOUT=64 PSTEP=2
// node rows nr = (b*64+i)*16 + r            (2048)
// edge rows er = ((b*64+i)*64 + j)*16 + r   (131072)
//
// R6 lessons: occupancy lever exhausted (30% occ, MfmaUtil 22% < VALUBusy
// 30%); the exposed cost is epilogue per-lane E2 global gathers + the
// 32-block node path. R7:
//  - E2 stored as bf16 r-major swizzled images [b][r][64j][256] (1MB);
//    kstep blocks DMA their 16KB half-tile to LDS in phase 0 and read E2
//    from LDS in the h-epilogue (was 32 global loads/lane).
//  - b1 folded into E1 (E1b) at the node kernels.
//  - node kernels widened to 64 blocks x 32 rows (MI=2).
//
// All GEMMs: v_mfma_f32_16x16x32_bf16. Weights pre-packed into fragment order
// with the SAME (lane,elem)->k map as the LDS A-fragment reads, so any k-map
// mismatch vs HW cancels. LDS tiles XOR-swizzled: byte ^= (row&7)<<4.

typedef __attribute__((ext_vector_type(8))) short short8;
typedef __attribute__((ext_vector_type(4))) float f32x4;
typedef __attribute__((ext_vector_type(2))) unsigned int u32x2;

#define DI __device__ __forceinline__

// ---------------- workspace layout (bytes) ----------------
constexpr size_t WF_SZ = 131072;            // 256x256 bf16 frag matrix
// full 256x256 frag matrices, index:
// 0 ep0W1c(=ep0W1[512:768]) 1 ep0W2 2 ep1W1c 3 ep1W2 4 prW1a(=prW1[0:256])
// 5 prW1b(=prW1[256:512]) 6 E1w(=ep0W1[0:256]) 7 E2w(=ep0W1[256:512])
// 8 NE2w(=npW1[256:512]) 9 NAGGw(=npW1[512:768]) 10 NE1w(=npW1[0:256])
// 11 npW2 12 ep1Aw(=ep1W1[0:256]) 13 ep1Bw(=ep1W1[256:512])
constexpr size_t OFF_NEW  = 14 * WF_SZ;      // neW   64x256 frag (32 KB)
constexpr size_t OFF_EE1  = OFF_NEW + 32768; // eeW[0:64]
constexpr size_t OFF_EE2  = OFF_EE1 + 32768; // eeW[64:128]
constexpr size_t OFF_PW2  = OFF_EE2 + 32768; // prW2 256x64 frag
constexpr size_t OFF_NENC = OFF_PW2 + 32768; // node_enc bf16 [2048,256] 1MB
constexpr size_t OFF_X1   = OFF_NENC + (size_t)2048 * 256 * 2;
constexpr size_t SM = (size_t)2048 * 256 * 4;
constexpr size_t OFF_X2   = OFF_X1 + SM;
constexpr size_t OFF_E1   = OFF_X2 + SM;          // E1b = E1 + b1, f32 [2048][256]
constexpr size_t OFF_E2I  = OFF_E1 + SM;          // E2 images: 32 x 32KB = 1MB
constexpr size_t OFF_NE1  = OFF_E2I + 32 * 32768;
constexpr size_t OFF_AGG  = OFF_NE1 + SM;         // 2 halves: 2 x 2MB
constexpr size_t OFF_IMG  = OFF_AGG + 2 * SM;     // eff images: 4096 x 16KB = 64 MiB
// total ~80 MB

DI unsigned short f2bf(float f) {
    unsigned u = __builtin_bit_cast(unsigned, f);
    u += 0x7fffu + ((u >> 16) & 1u);
    return (unsigned short)(u >> 16);
}
DI float bf2f(unsigned short s) {
    unsigned u = (unsigned)s << 16;
    return __builtin_bit_cast(float, u);
}

// (lane-group g, element e) -> k offset within a 32-wide K tile.
DI int kmap(int g, int e) { return 4 * g + (e & 3) + ((e >> 2) << 4); }

// async 16B/lane global->LDS copy (wave-uniform LDS base, per-lane global src)
DI void dma16(const void* g, void* l) {
    __builtin_amdgcn_global_load_lds((const __attribute__((address_space(1))) void*)g,
                                     (__attribute__((address_space(3))) void*)l, 16, 0, 0);
}

// ---------------- weight repack: f32 [K x ld] -> bf16 fragment order ----------------
__global__ __launch_bounds__(64) void kconv(const float* ep0W1, const float* ep0W2,
                                            const float* ep1W1, const float* ep1W2,
                                            const float* prW1, const float* prW2,
                                            const float* npW1, const float* npW2,
                                            const float* neW, const float* eeW,
                                            unsigned short* wsu)
{
    int bid = blockIdx.x, l = threadIdx.x;
    const float* src; unsigned short* dst; int NT = 16, ld = 256, f;
    if (bid < 1792) {
        int m = bid >> 7; f = bid & 127;
        switch (m) {
            case 0:  src = ep0W1 + 512 * 256; break;
            case 1:  src = ep0W2;             break;
            case 2:  src = ep1W1 + 512 * 256; break;
            case 3:  src = ep1W2;             break;
            case 4:  src = prW1;              break;
            case 5:  src = prW1 + 256 * 256;  break;
            case 6:  src = ep0W1;             break;
            case 7:  src = ep0W1 + 256 * 256; break;
            case 8:  src = npW1 + 256 * 256;  break;
            case 9:  src = npW1 + 512 * 256;  break;
            case 10: src = npW1;              break;
            case 11: src = npW2;              break;
            case 12: src = ep1W1;             break;
            default: src = ep1W1 + 256 * 256; break;
        }
        dst = wsu + (size_t)m * (WF_SZ / 2);
    } else if (bid < 1888) {
        int m = (bid - 1792) >> 5; f = (bid - 1792) & 31;
        src = (m == 0) ? neW : (m == 1) ? eeW : eeW + 64 * 256;
        dst = wsu + ((m == 0) ? OFF_NEW : (m == 1) ? OFF_EE1 : OFF_EE2) / 2;
    } else {
        f = bid - 1888; NT = 4; ld = 64; src = prW2; dst = wsu + OFF_PW2 / 2;
    }
    int kt = f / NT, nt = f % NT;
    int g = l >> 4, c = nt * 16 + (l & 15);
    unsigned short* o = dst + (size_t)((kt * NT + nt) * 64 + l) * 8;
#pragma unroll
    for (int e = 0; e < 8; ++e) {
        int k = 32 * kt + kmap(g, e);
        o[e] = f2bf(src[(size_t)k * ld + c]);
    }
}

// ---------------- MFMA tile helpers ----------------
// LDS tile: rows x (LDB bytes), XOR swizzle byte ^= (row&7)<<4
template <int LDB>
DI short8 load_afrag(const unsigned char* lds, int row, int kt, int g) {
    int sw = (row & 7) << 4;
    int kb = 64 * kt + 8 * g;
    union { short8 s; u32x2 u[2]; } u_;
    u_.u[0] = *(const u32x2*)(lds + row * LDB + (kb ^ sw));
    u_.u[1] = *(const u32x2*)(lds + row * LDB + ((kb + 32) ^ sw));
    return u_.s;
}

template <int MI>
DI void zero_acc(f32x4 (&acc)[MI][4]) {
#pragma unroll
    for (int mi = 0; mi < MI; ++mi)
#pragma unroll
        for (int ni = 0; ni < 4; ++ni) acc[mi][ni] = (f32x4){0.f, 0.f, 0.f, 0.f};
}

// acc += Atile(16*MI x 32*KT, LDS) @ W(32*KT x 256, frag order); wave wv owns cols 64*wv..+63
template <int MI, int KT, int LDB>
DI void gemm_tile(const unsigned char* lds, const unsigned short* Wf,
                  f32x4 (&acc)[MI][4], int wv, int l) {
    const int g = l >> 4, l15 = l & 15;
    for (int kt = 0; kt < KT; ++kt) {
        short8 af[MI];
#pragma unroll
        for (int mi = 0; mi < MI; ++mi) af[mi] = load_afrag<LDB>(lds, 16 * mi + l15, kt, g);
        short8 bf[4];
#pragma unroll
        for (int ni = 0; ni < 4; ++ni)
            bf[ni] = *(const short8*)(Wf + (size_t)((kt * 16 + 4 * wv + ni) * 64 + l) * 8);
#pragma unroll
        for (int ni = 0; ni < 4; ++ni)
#pragma unroll
            for (int mi = 0; mi < MI; ++mi)
                acc[mi][ni] = __builtin_amdgcn_mfma_f32_16x16x32_bf16(af[mi], bf[ni], acc[mi][ni], 0, 0, 0);
    }
}

template <int MI>
DI void store_tile_f32(float* dst, int r0, f32x4 (&acc)[MI][4], int wv, int l) {
    int g = l >> 4, l15 = l & 15;
#pragma unroll
    for (int ni = 0; ni < 4; ++ni) {
        int col = 64 * wv + 16 * ni + l15;
#pragma unroll
        for (int mi = 0; mi < MI; ++mi)
#pragma unroll
            for (int q = 0; q < 4; ++q)
                dst[(size_t)(r0 + 16 * mi + 4 * g + q) * 256 + col] = acc[mi][ni][q];
    }
}

// store acc + bias[col] as f32 (E1b = E1 + b1)
template <int MI>
DI void store_tile_bias(float* dst, const float* bias, int r0, f32x4 (&acc)[MI][4], int wv, int l) {
    int g = l >> 4, l15 = l & 15;
#pragma unroll
    for (int ni = 0; ni < 4; ++ni) {
        int col = 64 * wv + 16 * ni + l15;
        float bb = bias[col];
#pragma unroll
        for (int mi = 0; mi < MI; ++mi)
#pragma unroll
            for (int q = 0; q < 4; ++q)
                dst[(size_t)(r0 + 16 * mi + 4 * g + q) * 256 + col] = acc[mi][ni][q] + bb;
    }
}

// store to E2 image: [b][r] 32KB images, row j, XOR-swizzled bf16
template <int MI>
DI void store_E2img(unsigned char* E2img, int r0, f32x4 (&acc)[MI][4], int wv, int l) {
    int g = l >> 4, l15 = l & 15;
#pragma unroll
    for (int ni = 0; ni < 4; ++ni) {
        int col = 64 * wv + 16 * ni + l15;
#pragma unroll
        for (int mi = 0; mi < MI; ++mi)
#pragma unroll
            for (int q = 0; q < 4; ++q) {
                int nr = r0 + 16 * mi + 4 * g + q;
                int b = nr >> 10, j = (nr >> 4) & 63, r = nr & 15;
                size_t byte = (size_t)(b * 16 + r) * 32768 + ((j * 512 + col * 2) ^ ((j & 7) << 4));
                *(unsigned short*)(E2img + byte) = f2bf(acc[mi][ni][q]);
            }
    }
}

// ---------------- node path: encoder + edge-enc partials + E1b/E2img/NE1 ----------------
__global__ __launch_bounds__(256) void knode12(const float* node_rep, const float* neb,
        const float* ep0b1,
        const unsigned short* neWf, const unsigned short* eeW1f, const unsigned short* eeW2f,
        const unsigned short* E1wf, const unsigned short* E2wf, const unsigned short* NE1wf,
        unsigned short* node_enc, float* X1, float* X2, float* E1b, unsigned char* E2img, float* NE1)
{
    __shared__ __align__(16) unsigned char ldsA[32 * 128];
    __shared__ __align__(16) unsigned char ldsB[32 * 512];
    const int r0 = blockIdx.x * 32, tid = threadIdx.x;
    {
        int row = tid >> 3, c0 = (tid & 7) * 8;
        const float* src = node_rep + (size_t)(r0 + row) * 64 + c0;
        union { short8 s; unsigned short u[8]; } v;
#pragma unroll
        for (int e = 0; e < 8; ++e) v.u[e] = f2bf(src[e]);
        *(short8*)&ldsA[row * 128 + ((c0 * 2) ^ ((row & 7) << 4))] = v.s;
    }
    __syncthreads();
    const int l = tid & 63, wv = tid >> 6, g = l >> 4, l15 = l & 15;
    f32x4 acc[2][4];
    // node_enc = relu(node_rep @ neW + neb) -> bf16 ldsB + global
    zero_acc(acc);
    gemm_tile<2, 2, 128>(ldsA, neWf, acc, wv, l);
#pragma unroll
    for (int ni = 0; ni < 4; ++ni) {
        int col = 64 * wv + 16 * ni + l15;
        float bb = neb[col];
#pragma unroll
        for (int mi = 0; mi < 2; ++mi)
#pragma unroll
            for (int q = 0; q < 4; ++q) {
                int row = 16 * mi + 4 * g + q;
                unsigned short bv = f2bf(fmaxf(acc[mi][ni][q] + bb, 0.f));
                *(unsigned short*)&ldsB[row * 512 + ((col * 2) ^ ((row & 7) << 4))] = bv;
                node_enc[(size_t)(r0 + row) * 256 + col] = bv;
            }
    }
    // X1 = node_rep @ eeW[:64], X2 = node_rep @ eeW[64:]
    zero_acc(acc);
    gemm_tile<2, 2, 128>(ldsA, eeW1f, acc, wv, l);
    store_tile_f32<2>(X1, r0, acc, wv, l);
    zero_acc(acc);
    gemm_tile<2, 2, 128>(ldsA, eeW2f, acc, wv, l);
    store_tile_f32<2>(X2, r0, acc, wv, l);
    __syncthreads();   // all ldsB writes done before K=256 gemms read it
    zero_acc(acc);
    gemm_tile<2, 8, 512>(ldsB, E1wf, acc, wv, l);
    store_tile_bias<2>(E1b, ep0b1, r0, acc, wv, l);
    zero_acc(acc);
    gemm_tile<2, 8, 512>(ldsB, E2wf, acc, wv, l);
    store_E2img<2>(E2img, r0, acc, wv, l);
    zero_acc(acc);
    gemm_tile<2, 8, 512>(ldsB, NE1wf, acc, wv, l);
    store_tile_f32<2>(NE1, r0, acc, wv, l);
}

// ---------------- node update chain (step-1) + E1b_1/E2img_1 ----------------
__global__ __launch_bounds__(256) void knode3(const unsigned short* node_enc, const float* agg,
        const float* NE1, const float* npb1, const float* npb2, const float* ep1b1,
        const unsigned short* NE2wf, const unsigned short* NAGGwf, const unsigned short* npW2f,
        const unsigned short* ep1Awf, const unsigned short* ep1Bwf,
        float* E1b, unsigned char* E2img)
{
    __shared__ __align__(16) unsigned char ldsA[32 * 512];
    __shared__ __align__(16) unsigned char ldsB[32 * 512];
    const int r0 = blockIdx.x * 32, tid = threadIdx.x;
    {
        int row = tid >> 3, cbase = (tid & 7) * 32;
        int sw = (row & 7) << 4;
#pragma unroll
        for (int cc = 0; cc < 2; ++cc) {
            int c0 = cbase + cc * 16;
            short8 lo = *(const short8*)(node_enc + (size_t)(r0 + row) * 256 + c0);
            short8 hi = *(const short8*)(node_enc + (size_t)(r0 + row) * 256 + c0 + 8);
            *(short8*)&ldsA[row * 512 + ((c0 * 2) ^ sw)] = lo;
            *(short8*)&ldsA[row * 512 + ((c0 * 2 + 16) ^ sw)] = hi;
            union { short8 s; unsigned short u[8]; } v0, v1;
            const float* aA = agg + (size_t)(r0 + row) * 256 + c0;
            const float* aB = aA + (size_t)2048 * 256;   // second half-partial
#pragma unroll
            for (int e = 0; e < 8; ++e) {
                v0.u[e] = f2bf(aA[e] + aB[e]);
                v1.u[e] = f2bf(aA[8 + e] + aB[8 + e]);
            }
            *(short8*)&ldsB[row * 512 + ((c0 * 2) ^ sw)] = v0.s;
            *(short8*)&ldsB[row * 512 + ((c0 * 2 + 16) ^ sw)] = v1.s;
        }
    }
    __syncthreads();
    const int l = tid & 63, wv = tid >> 6, g = l >> 4, l15 = l & 15;
    f32x4 acc[2][4];
    // g = relu(NE1 + node_enc@NE2w + agg@NAGGw + npb1) -> bf16 ldsA
    zero_acc(acc);
    gemm_tile<2, 8, 512>(ldsA, NE2wf, acc, wv, l);
    gemm_tile<2, 8, 512>(ldsB, NAGGwf, acc, wv, l);
    __syncthreads();
#pragma unroll
    for (int ni = 0; ni < 4; ++ni) {
        int col = 64 * wv + 16 * ni + l15;
        float bb = npb1[col];
#pragma unroll
        for (int mi = 0; mi < 2; ++mi)
#pragma unroll
            for (int q = 0; q < 4; ++q) {
                int row = 16 * mi + 4 * g + q;
                float v = fmaxf(acc[mi][ni][q] + NE1[(size_t)(r0 + row) * 256 + col] + bb, 0.f);
                *(unsigned short*)&ldsA[row * 512 + ((col * 2) ^ ((row & 7) << 4))] = f2bf(v);
            }
    }
    __syncthreads();
    // nf = relu(g @ npW2 + npb2) -> bf16 ldsB
    zero_acc(acc);
    gemm_tile<2, 8, 512>(ldsA, npW2f, acc, wv, l);
    __syncthreads();
#pragma unroll
    for (int ni = 0; ni < 4; ++ni) {
        int col = 64 * wv + 16 * ni + l15;
        float bb = npb2[col];
#pragma unroll
        for (int mi = 0; mi < 2; ++mi)
#pragma unroll
            for (int q = 0; q < 4; ++q) {
                int row = 16 * mi + 4 * g + q;
                *(unsigned short*)&ldsB[row * 512 + ((col * 2) ^ ((row & 7) << 4))] =
                    f2bf(fmaxf(acc[mi][ni][q] + bb, 0.f));
            }
    }
    __syncthreads();
    // E1b = nf @ ep1W1[0:256] + ep1b1, E2img = nf @ ep1W1[256:512]
    zero_acc(acc);
    gemm_tile<2, 8, 512>(ldsB, ep1Awf, acc, wv, l);
    store_tile_bias<2>(E1b, ep1b1, r0, acc, wv, l);
    zero_acc(acc);
    gemm_tile<2, 8, 512>(ldsB, ep1Bwf, acc, wv, l);
    store_E2img<2>(E2img, r0, acc, wv, l);
}

// ---------------- fused edge propagation step 0, 32-row half-tiles ----------------
__global__ __launch_bounds__(256, 2) void kstep1(const float* X1, const float* X2, const float* eeb,
                                                 const float* E1b, const unsigned char* E2img,
                                                 const float* b2,
                                                 const unsigned short* WfA, const unsigned short* WfB,
                                                 unsigned char* img, float* agg)
{
    __shared__ __align__(16) unsigned char T[32 * 512];
    __shared__ __align__(16) unsigned char L2e[32 * 512];
    const int bb = blockIdx.x, tid = threadIdx.x;
    const int bir = bb >> 1, half = bb & 1;
    const int b = bir >> 10, r = bir & 15;
    const int l = tid & 63, wv = tid >> 6, g = l >> 4, l15 = l & 15;

    // issue E2 half-tile DMA first (overlaps the e0 VALU build below)
    {
        const unsigned char* src = E2img + (size_t)(b * 16 + r) * 32768 + (size_t)half * 16384;
#pragma unroll
        for (int p = 0; p < 4; ++p) {
            int chunk = wv * 4 + p;
            dma16(src + chunk * 1024 + l * 16, &L2e[chunk * 1024]);
        }
    }
    {   // phase 0: build e0 half-tile (rows = senders j = half*32 + row)
        int rlo = tid >> 5;
        int c0 = (tid & 31) * 8;
        for (int p = 0; p < 4; ++p) {
            int row = p * 8 + rlo;
            union { short8 s; unsigned short u[8]; } v;
            int nrj = b * 1024 + (half * 32 + row) * 16 + r;
#pragma unroll
            for (int e = 0; e < 8; ++e) {
                float x = X1[(size_t)bir * 256 + c0 + e] + X2[(size_t)nrj * 256 + c0 + e] + eeb[c0 + e];
                v.u[e] = f2bf(fmaxf(x, 0.f));
            }
            *(short8*)&T[row * 512 + ((c0 * 2) ^ ((row & 7) << 4))] = v.s;
        }
    }
    __syncthreads();

    f32x4 acc[2][4];
    zero_acc(acc);
    gemm_tile<2, 8, 512>(T, WfA, acc, wv, l);
    __syncthreads();
#pragma unroll
    for (int ni = 0; ni < 4; ++ni) {
        int col = 64 * wv + 16 * ni + l15;
        float e1b = E1b[(size_t)bir * 256 + col];
#pragma unroll
        for (int mi = 0; mi < 2; ++mi)
#pragma unroll
            for (int q = 0; q < 4; ++q) {
                int row = 16 * mi + 4 * g + q;
                float e2 = bf2f(*(const unsigned short*)&L2e[row * 512 + ((col * 2) ^ ((row & 7) << 4))]);
                float h = fmaxf(acc[mi][ni][q] + e1b + e2, 0.f);
                *(unsigned short*)&T[row * 512 + ((col * 2) ^ ((row & 7) << 4))] = f2bf(h);
                acc[mi][ni][q] = 0.f;
            }
    }
    __syncthreads();
    gemm_tile<2, 8, 512>(T, WfB, acc, wv, l);
    // epilogue: eff = relu(acc + b2) -> 16KB LDS-image in HBM + agg half-partial
    unsigned short* out16 = (unsigned short*)(img + (size_t)bb * 16384);
#pragma unroll
    for (int ni = 0; ni < 4; ++ni) {
        int col = 64 * wv + 16 * ni + l15;
        float bb2 = b2[col];
        float s = 0.f;
#pragma unroll
        for (int mi = 0; mi < 2; ++mi)
#pragma unroll
            for (int q = 0; q < 4; ++q) {
                int row = 16 * mi + 4 * g + q;
                float e = fmaxf(acc[mi][ni][q] + bb2, 0.f);
                out16[(row * 512 + ((col * 2) ^ ((row & 7) << 4))) >> 1] = f2bf(e);
                s += e;
            }
        s += __shfl_xor(s, 16);
        s += __shfl_xor(s, 32);
        if (l < 16) agg[((size_t)half * 2048 + bir) * 256 + 64 * wv + 16 * ni + l] = s;
    }
}

// ---------------- fused edge step 1 + predictor, 32-row half-tiles ----------------
__global__ __launch_bounds__(256, 2) void kstep2pred(const float* X1, const float* X2, const float* eeb,
        const float* E1b, const unsigned char* E2img, const float* b2,
        const unsigned short* WfA, const unsigned short* WfB,
        const unsigned short* WfPA, const unsigned short* WfPB, const unsigned short* WfP2,
        const float* prb1, const float* prb2,
        const unsigned char* img, float* out)
{
    __shared__ __align__(16) unsigned char T[32 * 512];
    __shared__ __align__(16) unsigned char L2e[32 * 512];
    const int bb = blockIdx.x, tid = threadIdx.x;
    const int bir = bb >> 1, half = bb & 1;
    const int b = bir >> 10, r = bir & 15;
    const int ebase = (bir >> 4) * 1024 + r;
    const int l = tid & 63, wv = tid >> 6, g = l >> 4, l15 = l & 15;

    // phase 0: async DMA eff image -> T, E2 half-tile -> L2e
    {
        const unsigned char* src = img + (size_t)bb * 16384;
        const unsigned char* srcE = E2img + (size_t)(b * 16 + r) * 32768 + (size_t)half * 16384;
#pragma unroll
        for (int p = 0; p < 4; ++p) {
            int chunk = wv * 4 + p;
            dma16(src + chunk * 1024 + l * 16, &T[chunk * 1024]);
            dma16(srcE + chunk * 1024 + l * 16, &L2e[chunk * 1024]);
        }
    }
    __syncthreads();

    f32x4 acc[2][4];
    // h = relu(eff @ ep1W1c + E1b + E2) -> T
    zero_acc(acc);
    gemm_tile<2, 8, 512>(T, WfA, acc, wv, l);
    __syncthreads();
#pragma unroll
    for (int ni = 0; ni < 4; ++ni) {
        int col = 64 * wv + 16 * ni + l15;
        float e1b = E1b[(size_t)bir * 256 + col];
#pragma unroll
        for (int mi = 0; mi < 2; ++mi)
#pragma unroll
            for (int q = 0; q < 4; ++q) {
                int row = 16 * mi + 4 * g + q;
                float e2 = bf2f(*(const unsigned short*)&L2e[row * 512 + ((col * 2) ^ ((row & 7) << 4))]);
                float h = fmaxf(acc[mi][ni][q] + e1b + e2, 0.f);
                *(unsigned short*)&T[row * 512 + ((col * 2) ^ ((row & 7) << 4))] = f2bf(h);
                acc[mi][ni][q] = 0.f;
            }
    }
    __syncthreads();
    // eff2 = relu(h @ ep1W2 + b2) -> T
    gemm_tile<2, 8, 512>(T, WfB, acc, wv, l);
    __syncthreads();
#pragma unroll
    for (int ni = 0; ni < 4; ++ni) {
        int col = 64 * wv + 16 * ni + l15;
        float bb2 = b2[col];
#pragma unroll
        for (int mi = 0; mi < 2; ++mi)
#pragma unroll
            for (int q = 0; q < 4; ++q) {
                int row = 16 * mi + 4 * g + q;
                *(unsigned short*)&T[row * 512 + ((col * 2) ^ ((row & 7) << 4))] =
                    f2bf(fmaxf(acc[mi][ni][q] + bb2, 0.f));
            }
    }
    __syncthreads();
    // acc = eff2 @ prW1a
    zero_acc(acc);
    gemm_tile<2, 8, 512>(T, WfPA, acc, wv, l);
    __syncthreads();
    // T <- e0 (recomputed; acc lives in regs across this)
    {
        int rlo = tid >> 5;
        int c0 = (tid & 31) * 8;
        for (int p = 0; p < 4; ++p) {
            int row = p * 8 + rlo;
            union { short8 s; unsigned short u[8]; } v;
            int nrj = b * 1024 + (half * 32 + row) * 16 + r;
#pragma unroll
            for (int e = 0; e < 8; ++e) {
                float x = X1[(size_t)bir * 256 + c0 + e] + X2[(size_t)nrj * 256 + c0 + e] + eeb[c0 + e];
                v.u[e] = f2bf(fmaxf(x, 0.f));
            }
            *(short8*)&T[row * 512 + ((c0 * 2) ^ ((row & 7) << 4))] = v.s;
        }
    }
    __syncthreads();
    // acc += e0 @ prW1b
    gemm_tile<2, 8, 512>(T, WfPB, acc, wv, l);
    __syncthreads();
    // T <- p = relu(acc + prb1)
#pragma unroll
    for (int ni = 0; ni < 4; ++ni) {
        int col = 64 * wv + 16 * ni + l15;
        float pb = prb1[col];
#pragma unroll
        for (int mi = 0; mi < 2; ++mi)
#pragma unroll
            for (int q = 0; q < 4; ++q) {
                int row = 16 * mi + 4 * g + q;
                float p = fmaxf(acc[mi][ni][q] + pb, 0.f);
                *(unsigned short*)&T[row * 512 + ((col * 2) ^ ((row & 7) << 4))] = f2bf(p);
            }
    }
    __syncthreads();
    // out = p @ prW2 + prb2 : 64 cols, wave wv owns cols 16*wv..+15
    f32x4 acc3[2];
#pragma unroll
    for (int mi = 0; mi < 2; ++mi) acc3[mi] = (f32x4){0.f, 0.f, 0.f, 0.f};
    for (int kt = 0; kt < 8; ++kt) {
        short8 bf = *(const short8*)(WfP2 + (size_t)((kt * 4 + wv) * 64 + l) * 8);
#pragma unroll
        for (int mi = 0; mi < 2; ++mi) {
            short8 af = load_afrag<512>(T, 16 * mi + l15, kt, g);
            acc3[mi] = __builtin_amdgcn_mfma_f32_16x16x32_bf16(af, bf, acc3[mi], 0, 0, 0);
        }
    }
    int colo = 16 * wv + l15;
    float pb2 = prb2[colo];
#pragma unroll
    for (int mi = 0; mi < 2; ++mi)
#pragma unroll
        for (int q = 0; q < 4; ++q) {
            int row = 16 * mi + 4 * g + q;
            out[(size_t)(ebase + (half * 32 + row) * 16) * 64 + colo] = acc3[mi][q] + pb2;
        }
}

// ---------------- host ----------------
extern "C" void kernel_launch(void* const* d_in, const int* in_sizes, int n_in,
                              void* d_out, int out_size, void* d_ws, size_t ws_size,
                              hipStream_t stream)
{
    (void)in_sizes; (void)n_in; (void)out_size; (void)ws_size;
    const float* node_rep = (const float*)d_in[0];
    const float* neW   = (const float*)d_in[1];
    const float* neb   = (const float*)d_in[2];
    const float* eeW   = (const float*)d_in[3];
    const float* eeb   = (const float*)d_in[4];
    const float* npW1  = (const float*)d_in[5];
    const float* npb1  = (const float*)d_in[6];
    const float* npW2  = (const float*)d_in[7];
    const float* npb2  = (const float*)d_in[8];
    const float* ep0W1 = (const float*)d_in[9];
    const float* ep0b1 = (const float*)d_in[10];
    const float* ep0W2 = (const float*)d_in[11];
    const float* ep0b2 = (const float*)d_in[12];
    const float* ep1W1 = (const float*)d_in[13];
    const float* ep1b1 = (const float*)d_in[14];
    const float* ep1W2 = (const float*)d_in[15];
    const float* ep1b2 = (const float*)d_in[16];
    const float* prW1  = (const float*)d_in[17];
    const float* prb1  = (const float*)d_in[18];
    const float* prW2  = (const float*)d_in[19];
    const float* prb2  = (const float*)d_in[20];

    char* ws = (char*)d_ws;
    unsigned short* wsu = (unsigned short*)ws;
    auto wfull = [&](int i) { return (const unsigned short*)(ws + (size_t)i * WF_SZ); };
    unsigned short* node_enc = (unsigned short*)(ws + OFF_NENC);
    float* X1   = (float*)(ws + OFF_X1);
    float* X2   = (float*)(ws + OFF_X2);
    float* E1b  = (float*)(ws + OFF_E1);
    unsigned char* E2img = (unsigned char*)(ws + OFF_E2I);
    float* NE1  = (float*)(ws + OFF_NE1);
    float* agg  = (float*)(ws + OFF_AGG);
    unsigned char* img = (unsigned char*)(ws + OFF_IMG);
    const unsigned short* neWf  = (const unsigned short*)(ws + OFF_NEW);
    const unsigned short* eeW1f = (const unsigned short*)(ws + OFF_EE1);
    const unsigned short* eeW2f = (const unsigned short*)(ws + OFF_EE2);
    const unsigned short* prW2f = (const unsigned short*)(ws + OFF_PW2);

    kconv<<<dim3(1920), dim3(64), 0, stream>>>(ep0W1, ep0W2, ep1W1, ep1W2, prW1, prW2,
                                               npW1, npW2, neW, eeW, wsu);
    knode12<<<dim3(64), dim3(256), 0, stream>>>(node_rep, neb, ep0b1, neWf, eeW1f, eeW2f,
                                                wfull(6), wfull(7), wfull(10),
                                                node_enc, X1, X2, E1b, E2img, NE1);
    kstep1<<<dim3(4096), dim3(256), 0, stream>>>(X1, X2, eeb, E1b, E2img, ep0b2,
                                                 wfull(0), wfull(1), img, agg);
    knode3<<<dim3(64), dim3(256), 0, stream>>>(node_enc, agg, NE1, npb1, npb2, ep1b1,
                                               wfull(8), wfull(9), wfull(11),
                                               wfull(12), wfull(13), E1b, E2img);
    kstep2pred<<<dim3(4096), dim3(256), 0, stream>>>(X1, X2, eeb, E1b, E2img, ep1b2,
                                                     wfull(2), wfull(3), wfull(4), wfull(5),
                                                     prW2f, prb1, prb2, img, (float*)d_out);
}

// Round 8
// 342.635 us; speedup vs baseline: 1.9237x; 1.0055x over previous
//
#include <hip/hip_runtime.h>
#include <hip/hip_bf16.h>

// PropNet fused MFMA-bf16 implementation for MI355X (gfx950).
// B=2 N=64 R=16 D=64 H=256 EOUT=64 PSTEP=2
// node rows nr = (b*64+i)*16 + r            (2048)
// edge rows er = ((b*64+i)*64 + j)*16 + r   (131072)
//
// R7 lesson: bottleneck is the barrier-serialized phase chain (10 phases,
// ~2 resident blocks/CU -> every phase latency exposed, MfmaUtil ~20%).
// R8: ping-pong the two 16KB LDS buffers so each phase = GEMM(buf A) +
// epilogue/build(buf B) in ONE barrier interval:
//   kstep2pred: DMA->T | WfA(T)+h->U | WfB(U)+eff2->T | WfPA(T)+e0->U |
//               WfPB(U)+p->T | final(T)+store   (5 barriers, was 9)
//   kstep1:     e0->T | WfA(T)+h->U | WfB(U)+eff-epi   (2 barriers, was 4)
// E2 back to plain f32 + coalesced global gather PRELOADED into regs before
// the gemm (hides under MFMAs); E2img deleted; E1b(+bias) fold kept.
//
// All GEMMs: v_mfma_f32_16x16x32_bf16. Weights pre-packed into fragment order
// with the SAME (lane,elem)->k map as the LDS A-fragment reads, so any k-map
// mismatch vs HW cancels. LDS tiles XOR-swizzled: byte ^= (row&7)<<4.

typedef __attribute__((ext_vector_type(8))) short short8;
typedef __attribute__((ext_vector_type(4))) float f32x4;
typedef __attribute__((ext_vector_type(2))) unsigned int u32x2;

#define DI __device__ __forceinline__

// ---------------- workspace layout (bytes) ----------------
constexpr size_t WF_SZ = 131072;            // 256x256 bf16 frag matrix
// 0 ep0W1c 1 ep0W2 2 ep1W1c 3 ep1W2 4 prW1a 5 prW1b 6 E1w 7 E2w
// 8 NE2w 9 NAGGw 10 NE1w 11 npW2 12 ep1Aw 13 ep1Bw
constexpr size_t OFF_NEW  = 14 * WF_SZ;      // neW 64x256 frag
constexpr size_t OFF_EE1  = OFF_NEW + 32768;
constexpr size_t OFF_EE2  = OFF_EE1 + 32768;
constexpr size_t OFF_PW2  = OFF_EE2 + 32768;
constexpr size_t OFF_NENC = OFF_PW2 + 32768; // node_enc bf16 [2048,256]
constexpr size_t OFF_X1   = OFF_NENC + (size_t)2048 * 256 * 2;
constexpr size_t SM = (size_t)2048 * 256 * 4;
constexpr size_t OFF_X2   = OFF_X1 + SM;
constexpr size_t OFF_E1   = OFF_X2 + SM;      // E1b = E1 + b1
constexpr size_t OFF_E2   = OFF_E1 + SM;      // E2 f32 [2048][256]
constexpr size_t OFF_NE1  = OFF_E2 + SM;
constexpr size_t OFF_AGG  = OFF_NE1 + SM;     // 2 halves: 2 x 2MB
constexpr size_t OFF_IMG  = OFF_AGG + 2 * SM; // eff images: 4096 x 16KB
// total ~82 MB

DI unsigned short f2bf(float f) {
    unsigned u = __builtin_bit_cast(unsigned, f);
    u += 0x7fffu + ((u >> 16) & 1u);
    return (unsigned short)(u >> 16);
}

DI int kmap(int g, int e) { return 4 * g + (e & 3) + ((e >> 2) << 4); }

DI void dma16(const void* g, void* l) {
    __builtin_amdgcn_global_load_lds((const __attribute__((address_space(1))) void*)g,
                                     (__attribute__((address_space(3))) void*)l, 16, 0, 0);
}

// ---------------- weight repack: f32 [K x ld] -> bf16 fragment order ----------------
__global__ __launch_bounds__(64) void kconv(const float* ep0W1, const float* ep0W2,
                                            const float* ep1W1, const float* ep1W2,
                                            const float* prW1, const float* prW2,
                                            const float* npW1, const float* npW2,
                                            const float* neW, const float* eeW,
                                            unsigned short* wsu)
{
    int bid = blockIdx.x, l = threadIdx.x;
    const float* src; unsigned short* dst; int NT = 16, ld = 256, f;
    if (bid < 1792) {
        int m = bid >> 7; f = bid & 127;
        switch (m) {
            case 0:  src = ep0W1 + 512 * 256; break;
            case 1:  src = ep0W2;             break;
            case 2:  src = ep1W1 + 512 * 256; break;
            case 3:  src = ep1W2;             break;
            case 4:  src = prW1;              break;
            case 5:  src = prW1 + 256 * 256;  break;
            case 6:  src = ep0W1;             break;
            case 7:  src = ep0W1 + 256 * 256; break;
            case 8:  src = npW1 + 256 * 256;  break;
            case 9:  src = npW1 + 512 * 256;  break;
            case 10: src = npW1;              break;
            case 11: src = npW2;              break;
            case 12: src = ep1W1;             break;
            default: src = ep1W1 + 256 * 256; break;
        }
        dst = wsu + (size_t)m * (WF_SZ / 2);
    } else if (bid < 1888) {
        int m = (bid - 1792) >> 5; f = (bid - 1792) & 31;
        src = (m == 0) ? neW : (m == 1) ? eeW : eeW + 64 * 256;
        dst = wsu + ((m == 0) ? OFF_NEW : (m == 1) ? OFF_EE1 : OFF_EE2) / 2;
    } else {
        f = bid - 1888; NT = 4; ld = 64; src = prW2; dst = wsu + OFF_PW2 / 2;
    }
    int kt = f / NT, nt = f % NT;
    int g = l >> 4, c = nt * 16 + (l & 15);
    unsigned short* o = dst + (size_t)((kt * NT + nt) * 64 + l) * 8;
#pragma unroll
    for (int e = 0; e < 8; ++e) {
        int k = 32 * kt + kmap(g, e);
        o[e] = f2bf(src[(size_t)k * ld + c]);
    }
}

// ---------------- MFMA tile helpers ----------------
template <int LDB>
DI short8 load_afrag(const unsigned char* lds, int row, int kt, int g) {
    int sw = (row & 7) << 4;
    int kb = 64 * kt + 8 * g;
    union { short8 s; u32x2 u[2]; } u_;
    u_.u[0] = *(const u32x2*)(lds + row * LDB + (kb ^ sw));
    u_.u[1] = *(const u32x2*)(lds + row * LDB + ((kb + 32) ^ sw));
    return u_.s;
}

template <int MI>
DI void zero_acc(f32x4 (&acc)[MI][4]) {
#pragma unroll
    for (int mi = 0; mi < MI; ++mi)
#pragma unroll
        for (int ni = 0; ni < 4; ++ni) acc[mi][ni] = (f32x4){0.f, 0.f, 0.f, 0.f};
}

template <int MI, int KT, int LDB>
DI void gemm_tile(const unsigned char* lds, const unsigned short* Wf,
                  f32x4 (&acc)[MI][4], int wv, int l) {
    const int g = l >> 4, l15 = l & 15;
    for (int kt = 0; kt < KT; ++kt) {
        short8 af[MI];
#pragma unroll
        for (int mi = 0; mi < MI; ++mi) af[mi] = load_afrag<LDB>(lds, 16 * mi + l15, kt, g);
        short8 bf[4];
#pragma unroll
        for (int ni = 0; ni < 4; ++ni)
            bf[ni] = *(const short8*)(Wf + (size_t)((kt * 16 + 4 * wv + ni) * 64 + l) * 8);
#pragma unroll
        for (int ni = 0; ni < 4; ++ni)
#pragma unroll
            for (int mi = 0; mi < MI; ++mi)
                acc[mi][ni] = __builtin_amdgcn_mfma_f32_16x16x32_bf16(af[mi], bf[ni], acc[mi][ni], 0, 0, 0);
    }
}

template <int MI>
DI void store_tile_f32(float* dst, int r0, f32x4 (&acc)[MI][4], int wv, int l) {
    int g = l >> 4, l15 = l & 15;
#pragma unroll
    for (int ni = 0; ni < 4; ++ni) {
        int col = 64 * wv + 16 * ni + l15;
#pragma unroll
        for (int mi = 0; mi < MI; ++mi)
#pragma unroll
            for (int q = 0; q < 4; ++q)
                dst[(size_t)(r0 + 16 * mi + 4 * g + q) * 256 + col] = acc[mi][ni][q];
    }
}

template <int MI>
DI void store_tile_bias(float* dst, const float* bias, int r0, f32x4 (&acc)[MI][4], int wv, int l) {
    int g = l >> 4, l15 = l & 15;
#pragma unroll
    for (int ni = 0; ni < 4; ++ni) {
        int col = 64 * wv + 16 * ni + l15;
        float bb = bias[col];
#pragma unroll
        for (int mi = 0; mi < MI; ++mi)
#pragma unroll
            for (int q = 0; q < 4; ++q)
                dst[(size_t)(r0 + 16 * mi + 4 * g + q) * 256 + col] = acc[mi][ni][q] + bb;
    }
}

// ---------------- node path: encoder + edge-enc partials + E1b/E2/NE1 ----------------
__global__ __launch_bounds__(256) void knode12(const float* node_rep, const float* neb,
        const float* ep0b1,
        const unsigned short* neWf, const unsigned short* eeW1f, const unsigned short* eeW2f,
        const unsigned short* E1wf, const unsigned short* E2wf, const unsigned short* NE1wf,
        unsigned short* node_enc, float* X1, float* X2, float* E1b, float* E2, float* NE1)
{
    __shared__ __align__(16) unsigned char ldsA[32 * 128];
    __shared__ __align__(16) unsigned char ldsB[32 * 512];
    const int r0 = blockIdx.x * 32, tid = threadIdx.x;
    {
        int row = tid >> 3, c0 = (tid & 7) * 8;
        const float* src = node_rep + (size_t)(r0 + row) * 64 + c0;
        union { short8 s; unsigned short u[8]; } v;
#pragma unroll
        for (int e = 0; e < 8; ++e) v.u[e] = f2bf(src[e]);
        *(short8*)&ldsA[row * 128 + ((c0 * 2) ^ ((row & 7) << 4))] = v.s;
    }
    __syncthreads();
    const int l = tid & 63, wv = tid >> 6, g = l >> 4, l15 = l & 15;
    f32x4 acc[2][4];
    zero_acc(acc);
    gemm_tile<2, 2, 128>(ldsA, neWf, acc, wv, l);
#pragma unroll
    for (int ni = 0; ni < 4; ++ni) {
        int col = 64 * wv + 16 * ni + l15;
        float bb = neb[col];
#pragma unroll
        for (int mi = 0; mi < 2; ++mi)
#pragma unroll
            for (int q = 0; q < 4; ++q) {
                int row = 16 * mi + 4 * g + q;
                unsigned short bv = f2bf(fmaxf(acc[mi][ni][q] + bb, 0.f));
                *(unsigned short*)&ldsB[row * 512 + ((col * 2) ^ ((row & 7) << 4))] = bv;
                node_enc[(size_t)(r0 + row) * 256 + col] = bv;
            }
    }
    zero_acc(acc);
    gemm_tile<2, 2, 128>(ldsA, eeW1f, acc, wv, l);
    store_tile_f32<2>(X1, r0, acc, wv, l);
    zero_acc(acc);
    gemm_tile<2, 2, 128>(ldsA, eeW2f, acc, wv, l);
    store_tile_f32<2>(X2, r0, acc, wv, l);
    __syncthreads();
    zero_acc(acc);
    gemm_tile<2, 8, 512>(ldsB, E1wf, acc, wv, l);
    store_tile_bias<2>(E1b, ep0b1, r0, acc, wv, l);
    zero_acc(acc);
    gemm_tile<2, 8, 512>(ldsB, E2wf, acc, wv, l);
    store_tile_f32<2>(E2, r0, acc, wv, l);
    zero_acc(acc);
    gemm_tile<2, 8, 512>(ldsB, NE1wf, acc, wv, l);
    store_tile_f32<2>(NE1, r0, acc, wv, l);
}

// ---------------- node update chain (step-1) + E1b_1/E2_1 ----------------
__global__ __launch_bounds__(256) void knode3(const unsigned short* node_enc, const float* agg,
        const float* NE1, const float* npb1, const float* npb2, const float* ep1b1,
        const unsigned short* NE2wf, const unsigned short* NAGGwf, const unsigned short* npW2f,
        const unsigned short* ep1Awf, const unsigned short* ep1Bwf,
        float* E1b, float* E2)
{
    __shared__ __align__(16) unsigned char ldsA[32 * 512];
    __shared__ __align__(16) unsigned char ldsB[32 * 512];
    const int r0 = blockIdx.x * 32, tid = threadIdx.x;
    {
        int row = tid >> 3, cbase = (tid & 7) * 32;
        int sw = (row & 7) << 4;
#pragma unroll
        for (int cc = 0; cc < 2; ++cc) {
            int c0 = cbase + cc * 16;
            short8 lo = *(const short8*)(node_enc + (size_t)(r0 + row) * 256 + c0);
            short8 hi = *(const short8*)(node_enc + (size_t)(r0 + row) * 256 + c0 + 8);
            *(short8*)&ldsA[row * 512 + ((c0 * 2) ^ sw)] = lo;
            *(short8*)&ldsA[row * 512 + ((c0 * 2 + 16) ^ sw)] = hi;
            union { short8 s; unsigned short u[8]; } v0, v1;
            const float* aA = agg + (size_t)(r0 + row) * 256 + c0;
            const float* aB = aA + (size_t)2048 * 256;
#pragma unroll
            for (int e = 0; e < 8; ++e) {
                v0.u[e] = f2bf(aA[e] + aB[e]);
                v1.u[e] = f2bf(aA[8 + e] + aB[8 + e]);
            }
            *(short8*)&ldsB[row * 512 + ((c0 * 2) ^ sw)] = v0.s;
            *(short8*)&ldsB[row * 512 + ((c0 * 2 + 16) ^ sw)] = v1.s;
        }
    }
    __syncthreads();
    const int l = tid & 63, wv = tid >> 6, g = l >> 4, l15 = l & 15;
    f32x4 acc[2][4];
    zero_acc(acc);
    gemm_tile<2, 8, 512>(ldsA, NE2wf, acc, wv, l);
    gemm_tile<2, 8, 512>(ldsB, NAGGwf, acc, wv, l);
    __syncthreads();
#pragma unroll
    for (int ni = 0; ni < 4; ++ni) {
        int col = 64 * wv + 16 * ni + l15;
        float bb = npb1[col];
#pragma unroll
        for (int mi = 0; mi < 2; ++mi)
#pragma unroll
            for (int q = 0; q < 4; ++q) {
                int row = 16 * mi + 4 * g + q;
                float v = fmaxf(acc[mi][ni][q] + NE1[(size_t)(r0 + row) * 256 + col] + bb, 0.f);
                *(unsigned short*)&ldsA[row * 512 + ((col * 2) ^ ((row & 7) << 4))] = f2bf(v);
            }
    }
    __syncthreads();
    zero_acc(acc);
    gemm_tile<2, 8, 512>(ldsA, npW2f, acc, wv, l);
    __syncthreads();
#pragma unroll
    for (int ni = 0; ni < 4; ++ni) {
        int col = 64 * wv + 16 * ni + l15;
        float bb = npb2[col];
#pragma unroll
        for (int mi = 0; mi < 2; ++mi)
#pragma unroll
            for (int q = 0; q < 4; ++q) {
                int row = 16 * mi + 4 * g + q;
                *(unsigned short*)&ldsB[row * 512 + ((col * 2) ^ ((row & 7) << 4))] =
                    f2bf(fmaxf(acc[mi][ni][q] + bb, 0.f));
            }
    }
    __syncthreads();
    zero_acc(acc);
    gemm_tile<2, 8, 512>(ldsB, ep1Awf, acc, wv, l);
    store_tile_bias<2>(E1b, ep1b1, r0, acc, wv, l);
    zero_acc(acc);
    gemm_tile<2, 8, 512>(ldsB, ep1Bwf, acc, wv, l);
    store_tile_f32<2>(E2, r0, acc, wv, l);
}

// ---------------- fused edge propagation step 0 (3-phase ping-pong) ----------------
__global__ __launch_bounds__(256, 2) void kstep1(const float* X1, const float* X2, const float* eeb,
                                                 const float* E1b, const float* E2, const float* b2,
                                                 const unsigned short* WfA, const unsigned short* WfB,
                                                 unsigned char* img, float* agg)
{
    __shared__ __align__(16) unsigned char T[32 * 512];
    __shared__ __align__(16) unsigned char U[32 * 512];
    const int bb = blockIdx.x, tid = threadIdx.x;
    const int bir = bb >> 1, half = bb & 1;
    const int b = bir >> 10, r = bir & 15;
    const int l = tid & 63, wv = tid >> 6, g = l >> 4, l15 = l & 15;

    // phase 0: e0 -> T
    {
        int rlo = tid >> 5, c0 = (tid & 31) * 8;
        for (int p = 0; p < 4; ++p) {
            int row = p * 8 + rlo;
            union { short8 s; unsigned short u[8]; } v;
            int nrj = b * 1024 + (half * 32 + row) * 16 + r;
#pragma unroll
            for (int e = 0; e < 8; ++e) {
                float x = X1[(size_t)bir * 256 + c0 + e] + X2[(size_t)nrj * 256 + c0 + e] + eeb[c0 + e];
                v.u[e] = f2bf(fmaxf(x, 0.f));
            }
            *(short8*)&T[row * 512 + ((c0 * 2) ^ ((row & 7) << 4))] = v.s;
        }
    }
    __syncthreads();

    // preload E2/E1b (latency hides under the gemm below)
    float e2p[4][8], e1p[4];
#pragma unroll
    for (int ni = 0; ni < 4; ++ni) {
        int col = 64 * wv + 16 * ni + l15;
        e1p[ni] = E1b[(size_t)bir * 256 + col];
#pragma unroll
        for (int mi = 0; mi < 2; ++mi)
#pragma unroll
            for (int q = 0; q < 4; ++q) {
                int row = 16 * mi + 4 * g + q;
                e2p[ni][mi * 4 + q] = E2[(size_t)(b * 1024 + (half * 32 + row) * 16 + r) * 256 + col];
            }
    }
    // phase 1: WfA(T) + h-epi -> U
    f32x4 acc[2][4];
    zero_acc(acc);
    gemm_tile<2, 8, 512>(T, WfA, acc, wv, l);
#pragma unroll
    for (int ni = 0; ni < 4; ++ni) {
        int col = 64 * wv + 16 * ni + l15;
#pragma unroll
        for (int mi = 0; mi < 2; ++mi)
#pragma unroll
            for (int q = 0; q < 4; ++q) {
                int row = 16 * mi + 4 * g + q;
                float h = fmaxf(acc[mi][ni][q] + e1p[ni] + e2p[ni][mi * 4 + q], 0.f);
                *(unsigned short*)&U[row * 512 + ((col * 2) ^ ((row & 7) << 4))] = f2bf(h);
                acc[mi][ni][q] = 0.f;
            }
    }
    __syncthreads();
    // phase 2: WfB(U) + eff-epi -> img + agg
    gemm_tile<2, 8, 512>(U, WfB, acc, wv, l);
    unsigned short* out16 = (unsigned short*)(img + (size_t)bb * 16384);
#pragma unroll
    for (int ni = 0; ni < 4; ++ni) {
        int col = 64 * wv + 16 * ni + l15;
        float bb2 = b2[col];
        float s = 0.f;
#pragma unroll
        for (int mi = 0; mi < 2; ++mi)
#pragma unroll
            for (int q = 0; q < 4; ++q) {
                int row = 16 * mi + 4 * g + q;
                float e = fmaxf(acc[mi][ni][q] + bb2, 0.f);
                out16[(row * 512 + ((col * 2) ^ ((row & 7) << 4))) >> 1] = f2bf(e);
                s += e;
            }
        s += __shfl_xor(s, 16);
        s += __shfl_xor(s, 32);
        if (l < 16) agg[((size_t)half * 2048 + bir) * 256 + 64 * wv + 16 * ni + l] = s;
    }
}

// ---------------- fused edge step 1 + predictor (6-phase ping-pong) ----------------
__global__ __launch_bounds__(256, 2) void kstep2pred(const float* X1, const float* X2, const float* eeb,
        const float* E1b, const float* E2, const float* b2,
        const unsigned short* WfA, const unsigned short* WfB,
        const unsigned short* WfPA, const unsigned short* WfPB, const unsigned short* WfP2,
        const float* prb1, const float* prb2,
        const unsigned char* img, float* out)
{
    __shared__ __align__(16) unsigned char T[32 * 512];
    __shared__ __align__(16) unsigned char U[32 * 512];
    const int bb = blockIdx.x, tid = threadIdx.x;
    const int bir = bb >> 1, half = bb & 1;
    const int b = bir >> 10, r = bir & 15;
    const int ebase = (bir >> 4) * 1024 + r;
    const int l = tid & 63, wv = tid >> 6, g = l >> 4, l15 = l & 15;

    // phase 0: DMA eff image -> T; E2/E1b preload overlaps the DMA wait
    {
        const unsigned char* src = img + (size_t)bb * 16384;
#pragma unroll
        for (int p = 0; p < 4; ++p) {
            int chunk = wv * 4 + p;
            dma16(src + chunk * 1024 + l * 16, &T[chunk * 1024]);
        }
    }
    float e2p[4][8], e1p[4];
#pragma unroll
    for (int ni = 0; ni < 4; ++ni) {
        int col = 64 * wv + 16 * ni + l15;
        e1p[ni] = E1b[(size_t)bir * 256 + col];
#pragma unroll
        for (int mi = 0; mi < 2; ++mi)
#pragma unroll
            for (int q = 0; q < 4; ++q) {
                int row = 16 * mi + 4 * g + q;
                e2p[ni][mi * 4 + q] = E2[(size_t)(b * 1024 + (half * 32 + row) * 16 + r) * 256 + col];
            }
    }
    __syncthreads();

    f32x4 acc[2][4];
    // phase 1: WfA(T) + h-epi -> U
    zero_acc(acc);
    gemm_tile<2, 8, 512>(T, WfA, acc, wv, l);
#pragma unroll
    for (int ni = 0; ni < 4; ++ni) {
        int col = 64 * wv + 16 * ni + l15;
#pragma unroll
        for (int mi = 0; mi < 2; ++mi)
#pragma unroll
            for (int q = 0; q < 4; ++q) {
                int row = 16 * mi + 4 * g + q;
                float h = fmaxf(acc[mi][ni][q] + e1p[ni] + e2p[ni][mi * 4 + q], 0.f);
                *(unsigned short*)&U[row * 512 + ((col * 2) ^ ((row & 7) << 4))] = f2bf(h);
                acc[mi][ni][q] = 0.f;
            }
    }
    __syncthreads();
    // phase 2: WfB(U) + eff2-epi -> T
    gemm_tile<2, 8, 512>(U, WfB, acc, wv, l);
#pragma unroll
    for (int ni = 0; ni < 4; ++ni) {
        int col = 64 * wv + 16 * ni + l15;
        float bb2 = b2[col];
#pragma unroll
        for (int mi = 0; mi < 2; ++mi)
#pragma unroll
            for (int q = 0; q < 4; ++q) {
                int row = 16 * mi + 4 * g + q;
                *(unsigned short*)&T[row * 512 + ((col * 2) ^ ((row & 7) << 4))] =
                    f2bf(fmaxf(acc[mi][ni][q] + bb2, 0.f));
                acc[mi][ni][q] = 0.f;
            }
    }
    __syncthreads();
    // phase 3: WfPA(T) + e0-build -> U (X1/X2 loads hide under MFMAs)
    gemm_tile<2, 8, 512>(T, WfPA, acc, wv, l);
    {
        int rlo = tid >> 5, c0 = (tid & 31) * 8;
        for (int p = 0; p < 4; ++p) {
            int row = p * 8 + rlo;
            union { short8 s; unsigned short u[8]; } v;
            int nrj = b * 1024 + (half * 32 + row) * 16 + r;
#pragma unroll
            for (int e = 0; e < 8; ++e) {
                float x = X1[(size_t)bir * 256 + c0 + e] + X2[(size_t)nrj * 256 + c0 + e] + eeb[c0 + e];
                v.u[e] = f2bf(fmaxf(x, 0.f));
            }
            *(short8*)&U[row * 512 + ((c0 * 2) ^ ((row & 7) << 4))] = v.s;
        }
    }
    __syncthreads();
    // phase 4: WfPB(U) + p-epi -> T
    gemm_tile<2, 8, 512>(U, WfPB, acc, wv, l);
#pragma unroll
    for (int ni = 0; ni < 4; ++ni) {
        int col = 64 * wv + 16 * ni + l15;
        float pb = prb1[col];
#pragma unroll
        for (int mi = 0; mi < 2; ++mi)
#pragma unroll
            for (int q = 0; q < 4; ++q) {
                int row = 16 * mi + 4 * g + q;
                float p = fmaxf(acc[mi][ni][q] + pb, 0.f);
                *(unsigned short*)&T[row * 512 + ((col * 2) ^ ((row & 7) << 4))] = f2bf(p);
            }
    }
    __syncthreads();
    // phase 5: final gemm(T) + out store
    f32x4 acc3[2];
#pragma unroll
    for (int mi = 0; mi < 2; ++mi) acc3[mi] = (f32x4){0.f, 0.f, 0.f, 0.f};
    for (int kt = 0; kt < 8; ++kt) {
        short8 bf = *(const short8*)(WfP2 + (size_t)((kt * 4 + wv) * 64 + l) * 8);
#pragma unroll
        for (int mi = 0; mi < 2; ++mi) {
            short8 af = load_afrag<512>(T, 16 * mi + l15, kt, g);
            acc3[mi] = __builtin_amdgcn_mfma_f32_16x16x32_bf16(af, bf, acc3[mi], 0, 0, 0);
        }
    }
    int colo = 16 * wv + l15;
    float pb2 = prb2[colo];
#pragma unroll
    for (int mi = 0; mi < 2; ++mi)
#pragma unroll
        for (int q = 0; q < 4; ++q) {
            int row = 16 * mi + 4 * g + q;
            out[(size_t)(ebase + (half * 32 + row) * 16) * 64 + colo] = acc3[mi][q] + pb2;
        }
}

// ---------------- host ----------------
extern "C" void kernel_launch(void* const* d_in, const int* in_sizes, int n_in,
                              void* d_out, int out_size, void* d_ws, size_t ws_size,
                              hipStream_t stream)
{
    (void)in_sizes; (void)n_in; (void)out_size; (void)ws_size;
    const float* node_rep = (const float*)d_in[0];
    const float* neW   = (const float*)d_in[1];
    const float* neb   = (const float*)d_in[2];
    const float* eeW   = (const float*)d_in[3];
    const float* eeb   = (const float*)d_in[4];
    const float* npW1  = (const float*)d_in[5];
    const float* npb1  = (const float*)d_in[6];
    const float* npW2  = (const float*)d_in[7];
    const float* npb2  = (const float*)d_in[8];
    const float* ep0W1 = (const float*)d_in[9];
    const float* ep0b1 = (const float*)d_in[10];
    const float* ep0W2 = (const float*)d_in[11];
    const float* ep0b2 = (const float*)d_in[12];
    const float* ep1W1 = (const float*)d_in[13];
    const float* ep1b1 = (const float*)d_in[14];
    const float* ep1W2 = (const float*)d_in[15];
    const float* ep1b2 = (const float*)d_in[16];
    const float* prW1  = (const float*)d_in[17];
    const float* prb1  = (const float*)d_in[18];
    const float* prW2  = (const float*)d_in[19];
    const float* prb2  = (const float*)d_in[20];

    char* ws = (char*)d_ws;
    unsigned short* wsu = (unsigned short*)ws;
    auto wfull = [&](int i) { return (const unsigned short*)(ws + (size_t)i * WF_SZ); };
    unsigned short* node_enc = (unsigned short*)(ws + OFF_NENC);
    float* X1   = (float*)(ws + OFF_X1);
    float* X2   = (float*)(ws + OFF_X2);
    float* E1b  = (float*)(ws + OFF_E1);
    float* E2   = (float*)(ws + OFF_E2);
    float* NE1  = (float*)(ws + OFF_NE1);
    float* agg  = (float*)(ws + OFF_AGG);
    unsigned char* img = (unsigned char*)(ws + OFF_IMG);
    const unsigned short* neWf  = (const unsigned short*)(ws + OFF_NEW);
    const unsigned short* eeW1f = (const unsigned short*)(ws + OFF_EE1);
    const unsigned short* eeW2f = (const unsigned short*)(ws + OFF_EE2);
    const unsigned short* prW2f = (const unsigned short*)(ws + OFF_PW2);

    kconv<<<dim3(1920), dim3(64), 0, stream>>>(ep0W1, ep0W2, ep1W1, ep1W2, prW1, prW2,
                                               npW1, npW2, neW, eeW, wsu);
    knode12<<<dim3(64), dim3(256), 0, stream>>>(node_rep, neb, ep0b1, neWf, eeW1f, eeW2f,
                                                wfull(6), wfull(7), wfull(10),
                                                node_enc, X1, X2, E1b, E2, NE1);
    kstep1<<<dim3(4096), dim3(256), 0, stream>>>(X1, X2, eeb, E1b, E2, ep0b2,
                                                 wfull(0), wfull(1), img, agg);
    knode3<<<dim3(64), dim3(256), 0, stream>>>(node_enc, agg, NE1, npb1, npb2, ep1b1,
                                               wfull(8), wfull(9), wfull(11),
                                               wfull(12), wfull(13), E1b, E2);
    kstep2pred<<<dim3(4096), dim3(256), 0, stream>>>(X1, X2, eeb, E1b, E2, ep1b2,
                                                     wfull(2), wfull(3), wfull(4), wfull(5),
                                                     prW2f, prb1, prb2, img, (float*)d_out);
}